// Round 1
// baseline (1120.001 us; speedup 1.0000x reference)
//
#include <hip/hip_runtime.h>
#include <hip/hip_bf16.h>

#define N_NODES 100000
#define E_EDGES 1600000
#define NG 512
#define FIN 7
#define HID 128
#define NB_SCAN 98   // ceil(N_NODES/1024)

// ---------------- CSR build ----------------

__global__ void k_count(const int* __restrict__ eidx, int* __restrict__ cnt) {
    int e = blockIdx.x * blockDim.x + threadIdx.x;
    if (e >= E_EDGES) return;
    int d = eidx[E_EDGES + e];   // dst
    atomicAdd(&cnt[d], 1);
}

__global__ void k_blocksum(const int* __restrict__ cnt, int* __restrict__ blksum) {
    __shared__ int s[256];
    int b = blockIdx.x, t = threadIdx.x;
    int base = b * 1024;
    int sum = 0;
    for (int i = t; i < 1024; i += 256) {
        int idx = base + i;
        sum += (idx < N_NODES) ? cnt[idx] : 0;
    }
    s[t] = sum; __syncthreads();
    for (int st = 128; st > 0; st >>= 1) {
        if (t < st) s[t] += s[t + st];
        __syncthreads();
    }
    if (t == 0) blksum[b] = s[0];
}

__global__ void k_scan_blk(int* __restrict__ blksum) {
    if (threadIdx.x == 0 && blockIdx.x == 0) {
        int run = 0;
        for (int i = 0; i < NB_SCAN; ++i) { int v = blksum[i]; blksum[i] = run; run += v; }
    }
}

__global__ void k_scan_final(const int* __restrict__ cnt, const int* __restrict__ blksum,
                             int* __restrict__ rowptr) {
    __shared__ int s[1024];
    int b = blockIdx.x, t = threadIdx.x;
    int idx = b * 1024 + t;
    int v = (idx < N_NODES) ? cnt[idx] : 0;
    s[t] = v; __syncthreads();
    for (int st = 1; st < 1024; st <<= 1) {
        int add = (t >= st) ? s[t - st] : 0;
        __syncthreads();
        s[t] += add;
        __syncthreads();
    }
    if (idx < N_NODES) rowptr[idx] = blksum[b] + s[t] - v;   // exclusive
    if (b == 0 && t == 0) rowptr[N_NODES] = E_EDGES;
}

__global__ void k_dinv(const int* __restrict__ cnt, float* __restrict__ dinv) {
    int i = blockIdx.x * blockDim.x + threadIdx.x;
    if (i >= N_NODES) return;
    float deg = (float)(cnt[i] + 1);   // +1 self loop, always > 0
    dinv[i] = rsqrtf(deg);
}

__global__ void k_fill(const int* __restrict__ eidx, const int* __restrict__ rowptr,
                       int* __restrict__ cursor, int* __restrict__ col) {
    int e = blockIdx.x * blockDim.x + threadIdx.x;
    if (e >= E_EDGES) return;
    int srcv = eidx[e];
    int d = eidx[E_EDGES + e];
    int p = rowptr[d] + atomicAdd(&cursor[d], 1);
    col[p] = srcv;
}

// ---------------- layer 1 aggregation (7-wide) ----------------

__global__ void k_agg7(const float* __restrict__ x, const int* __restrict__ rowptr,
                       const int* __restrict__ col, const float* __restrict__ dinv,
                       float* __restrict__ aggx) {
    int i = blockIdx.x * blockDim.x + threadIdx.x;
    if (i >= N_NODES) return;
    float di = dinv[i];
    float a[FIN];
    #pragma unroll
    for (int f = 0; f < FIN; ++f) a[f] = di * x[i * FIN + f];
    int e0 = rowptr[i], e1 = rowptr[i + 1];
    for (int e = e0; e < e1; ++e) {
        int s = col[e];
        float ds = dinv[s];
        #pragma unroll
        for (int f = 0; f < FIN; ++f) a[f] += ds * x[s * FIN + f];
    }
    #pragma unroll
    for (int f = 0; f < FIN; ++f) aggx[i * FIN + f] = di * a[f];
}

__global__ void k_mm1(const float* __restrict__ aggx, const float* __restrict__ W1,
                      const float* __restrict__ b1, float* __restrict__ out) {
    int idx = blockIdx.x * blockDim.x + threadIdx.x;
    if (idx >= N_NODES * HID) return;
    int n = idx >> 7, f = idx & 127;
    float acc = b1[f];
    #pragma unroll
    for (int k = 0; k < FIN; ++k) acc += aggx[n * FIN + k] * W1[k * HID + f];
    out[idx] = acc;
}

// ---------------- 128-wide aggregation (wave per node) ----------------

template <bool RELU>
__global__ void k_agg128(const float* __restrict__ in, float* __restrict__ out,
                         const int* __restrict__ rowptr, const int* __restrict__ col,
                         const float* __restrict__ dinv) {
    int wid = (blockIdx.x * blockDim.x + threadIdx.x) >> 6;
    int lane = threadIdx.x & 63;
    if (wid >= N_NODES) return;
    int i = wid;
    float di = dinv[i];
    float2 v = *(const float2*)&in[i * HID + 2 * lane];
    if (RELU) { v.x = fmaxf(v.x, 0.f); v.y = fmaxf(v.y, 0.f); }
    float ax = di * v.x, ay = di * v.y;
    int e0 = rowptr[i], e1 = rowptr[i + 1];
    for (int e = e0; e < e1; ++e) {
        int s = col[e];
        float ds = dinv[s];
        float2 u = *(const float2*)&in[s * HID + 2 * lane];
        if (RELU) { u.x = fmaxf(u.x, 0.f); u.y = fmaxf(u.y, 0.f); }
        ax += ds * u.x; ay += ds * u.y;
    }
    float2 o; o.x = di * ax; o.y = di * ay;
    *(float2*)&out[i * HID + 2 * lane] = o;
}

// ---------------- 128x128 matmul, fp32, register-tiled ----------------

__global__ __launch_bounds__(256) void k_mm128(const float* __restrict__ in,
                                               float* __restrict__ out,
                                               const float* __restrict__ W,
                                               const float* __restrict__ bias) {
    __shared__ float Ws[64 * 128];   // 32 KB (one k-half of W)
    __shared__ float rT[128 * 36];   // 18 KB (32-node tile, k-major, padded)
    int t = threadIdx.x;
    int base = blockIdx.x * 32;

    // stage transposed input tile
    for (int i = t; i < 32 * 128; i += 256) {
        int n = i >> 7, k = i & 127;
        int node = base + n;
        float v = (node < N_NODES) ? in[node * HID + k] : 0.f;
        rT[k * 36 + n] = v;
    }

    int f0 = (t & 31) << 2;   // features f0..f0+3
    int m0 = (t >> 5) << 2;   // nodes m0..m0+3 (within tile)
    float acc[4][4] = {};

    for (int kb = 0; kb < 128; kb += 64) {
        __syncthreads();
        for (int i = t; i < 64 * 128; i += 256)
            Ws[i] = W[(kb + (i >> 7)) * HID + (i & 127)];
        __syncthreads();
        #pragma unroll 4
        for (int kk = 0; kk < 64; ++kk) {
            int k = kb + kk;
            float4 w = *(const float4*)&Ws[kk * 128 + f0];
            float4 r = *(const float4*)&rT[k * 36 + m0];
            acc[0][0] += r.x * w.x; acc[0][1] += r.x * w.y; acc[0][2] += r.x * w.z; acc[0][3] += r.x * w.w;
            acc[1][0] += r.y * w.x; acc[1][1] += r.y * w.y; acc[1][2] += r.y * w.z; acc[1][3] += r.y * w.w;
            acc[2][0] += r.z * w.x; acc[2][1] += r.z * w.y; acc[2][2] += r.z * w.z; acc[2][3] += r.z * w.w;
            acc[3][0] += r.w * w.x; acc[3][1] += r.w * w.y; acc[3][2] += r.w * w.z; acc[3][3] += r.w * w.w;
        }
    }

    float4 bb = *(const float4*)&bias[f0];
    #pragma unroll
    for (int j = 0; j < 4; ++j) {
        int node = base + m0 + j;
        if (node < N_NODES) {
            float4 o;
            o.x = acc[j][0] + bb.x; o.y = acc[j][1] + bb.y;
            o.z = acc[j][2] + bb.z; o.w = acc[j][3] + bb.w;
            *(float4*)&out[node * HID + f0] = o;
        }
    }
}

// ---------------- pool + linear head ----------------

__global__ void k_pool(const float* __restrict__ h, const int* __restrict__ batch,
                       const float* __restrict__ Wlin, const float* __restrict__ blin,
                       float* __restrict__ out) {
    int wid = (blockIdx.x * blockDim.x + threadIdx.x) >> 6;
    int lane = threadIdx.x & 63;
    if (wid >= NG) return;
    int g = wid;
    // lower_bound(g)
    int lo = 0, hi = N_NODES;
    while (lo < hi) { int mid = (lo + hi) >> 1; if (batch[mid] < g) lo = mid + 1; else hi = mid; }
    int start = lo;
    hi = N_NODES;
    while (lo < hi) { int mid = (lo + hi) >> 1; if (batch[mid] < g + 1) lo = mid + 1; else hi = mid; }
    int end = lo;

    float sx = 0.f, sy = 0.f;   // features 2*lane, 2*lane+1
    for (int i = start; i < end; ++i) {
        float2 v = *(const float2*)&h[i * HID + 2 * lane];
        sx += v.x; sy += v.y;
    }
    float invc = (end > start) ? 1.0f / (float)(end - start) : 0.f;
    float px = sx * invc, py = sy * invc;

    #pragma unroll
    for (int o = 0; o < 2; ++o) {
        float v = px * Wlin[(2 * lane) * 2 + o] + py * Wlin[(2 * lane + 1) * 2 + o];
        #pragma unroll
        for (int s = 32; s > 0; s >>= 1) v += __shfl_down(v, s);
        if (lane == 0) out[g * 2 + o] = v + blin[o];
    }
}

// ---------------- launcher ----------------

extern "C" void kernel_launch(void* const* d_in, const int* in_sizes, int n_in,
                              void* d_out, int out_size, void* d_ws, size_t ws_size,
                              hipStream_t stream) {
    const float* x    = (const float*)d_in[0];
    const int*   eidx = (const int*)d_in[1];
    const int*   batch= (const int*)d_in[2];
    const float* W1   = (const float*)d_in[3];
    const float* b1   = (const float*)d_in[4];
    const float* W2   = (const float*)d_in[5];
    const float* b2   = (const float*)d_in[6];
    const float* W3   = (const float*)d_in[7];
    const float* b3   = (const float*)d_in[8];
    const float* W4   = (const float*)d_in[9];
    const float* b4   = (const float*)d_in[10];
    const float* Wlin = (const float*)d_in[11];
    const float* blin = (const float*)d_in[12];
    float* out = (float*)d_out;

    // workspace carve-up (256B aligned)
    char* ws = (char*)d_ws;
    size_t off = 0;
    auto carve = [&](size_t bytes) { char* p = ws + off; off = (off + bytes + 255) & ~(size_t)255; return p; };
    int*   cnt    = (int*)carve((size_t)N_NODES * 4);          // degree counts, later cursor
    int*   rowptr = (int*)carve((size_t)(N_NODES + 1) * 4);
    int*   blksum = (int*)carve((size_t)NB_SCAN * 4);
    float* dinv   = (float*)carve((size_t)N_NODES * 4);
    int*   col    = (int*)carve((size_t)E_EDGES * 4);
    float* aggx   = (float*)carve((size_t)N_NODES * FIN * 4);
    float* hA     = (float*)carve((size_t)N_NODES * HID * 4);
    float* hB     = (float*)carve((size_t)N_NODES * HID * 4);
    (void)ws_size; (void)n_in; (void)in_sizes; (void)out_size;

    const int BLK = 256;
    int gridE = (E_EDGES + BLK - 1) / BLK;          // 6250
    int gridN = (N_NODES + BLK - 1) / BLK;          // 391
    int gridAgg = (N_NODES * 64 + BLK - 1) / BLK;   // 25000 (wave per node)
    int gridMM = (N_NODES + 31) / 32;               // 3125
    int gridMM1 = (N_NODES * HID + BLK - 1) / BLK;  // 50000
    int gridPool = (NG * 64 + BLK - 1) / BLK;       // 128

    // CSR build
    hipMemsetAsync(cnt, 0, (size_t)N_NODES * 4, stream);
    k_count<<<gridE, BLK, 0, stream>>>(eidx, cnt);
    k_blocksum<<<NB_SCAN, BLK, 0, stream>>>(cnt, blksum);
    k_scan_blk<<<1, 64, 0, stream>>>(blksum);
    k_scan_final<<<NB_SCAN, 1024, 0, stream>>>(cnt, blksum, rowptr);
    k_dinv<<<gridN, BLK, 0, stream>>>(cnt, dinv);
    hipMemsetAsync(cnt, 0, (size_t)N_NODES * 4, stream);   // reuse as cursor
    k_fill<<<gridE, BLK, 0, stream>>>(eidx, rowptr, cnt, col);

    // layer 1: h = (A' x) W1 + b1
    k_agg7<<<gridN, BLK, 0, stream>>>(x, rowptr, col, dinv, aggx);
    k_mm1<<<gridMM1, BLK, 0, stream>>>(aggx, W1, b1, hA);

    // layers 2..4: h = (A' relu(h)) W + b
    k_agg128<true><<<gridAgg, BLK, 0, stream>>>(hA, hB, rowptr, col, dinv);
    k_mm128<<<gridMM, BLK, 0, stream>>>(hB, hA, W2, b2);
    k_agg128<true><<<gridAgg, BLK, 0, stream>>>(hA, hB, rowptr, col, dinv);
    k_mm128<<<gridMM, BLK, 0, stream>>>(hB, hA, W3, b3);
    k_agg128<true><<<gridAgg, BLK, 0, stream>>>(hA, hB, rowptr, col, dinv);
    k_mm128<<<gridMM, BLK, 0, stream>>>(hB, hA, W4, b4);

    // pool + head
    k_pool<<<gridPool, BLK, 0, stream>>>(hA, batch, Wlin, blin, out);
}

// Round 2
// 895.336 us; speedup vs baseline: 1.2509x; 1.2509x over previous
//
#include <hip/hip_runtime.h>
#include <hip/hip_bf16.h>

#define N_NODES 100000
#define E_EDGES 1600000
#define NG 512
#define FIN 7
#define HID 128
#define NB_SCAN 98   // ceil(N_NODES/1024)

// bf16 helpers: decode packed pair, encode with RNE
__device__ __forceinline__ float bf_lo(unsigned int u) { return __uint_as_float(u << 16); }
__device__ __forceinline__ float bf_hi(unsigned int u) { return __uint_as_float(u & 0xffff0000u); }
__device__ __forceinline__ unsigned int f2bf_rne(float f) {
    unsigned int x = __float_as_uint(f);
    return (x + 0x7fffu + ((x >> 16) & 1u)) >> 16;   // finite inputs only
}
__device__ __forceinline__ unsigned int pack_bf2(float lo, float hi) {
    return f2bf_rne(lo) | (f2bf_rne(hi) << 16);
}

// ---------------- CSR build ----------------

__global__ void k_count(const int* __restrict__ eidx, int* __restrict__ cnt) {
    int e = blockIdx.x * blockDim.x + threadIdx.x;
    if (e >= E_EDGES) return;
    int d = eidx[E_EDGES + e];   // dst
    atomicAdd(&cnt[d], 1);
}

__global__ void k_blocksum(const int* __restrict__ cnt, int* __restrict__ blksum) {
    __shared__ int s[256];
    int b = blockIdx.x, t = threadIdx.x;
    int base = b * 1024;
    int sum = 0;
    for (int i = t; i < 1024; i += 256) {
        int idx = base + i;
        sum += (idx < N_NODES) ? cnt[idx] : 0;
    }
    s[t] = sum; __syncthreads();
    for (int st = 128; st > 0; st >>= 1) {
        if (t < st) s[t] += s[t + st];
        __syncthreads();
    }
    if (t == 0) blksum[b] = s[0];
}

__global__ void k_scan_blk(int* __restrict__ blksum) {
    if (threadIdx.x == 0 && blockIdx.x == 0) {
        int run = 0;
        for (int i = 0; i < NB_SCAN; ++i) { int v = blksum[i]; blksum[i] = run; run += v; }
    }
}

__global__ void k_scan_final(const int* __restrict__ cnt, const int* __restrict__ blksum,
                             int* __restrict__ rowptr) {
    __shared__ int s[1024];
    int b = blockIdx.x, t = threadIdx.x;
    int idx = b * 1024 + t;
    int v = (idx < N_NODES) ? cnt[idx] : 0;
    s[t] = v; __syncthreads();
    for (int st = 1; st < 1024; st <<= 1) {
        int add = (t >= st) ? s[t - st] : 0;
        __syncthreads();
        s[t] += add;
        __syncthreads();
    }
    if (idx < N_NODES) rowptr[idx] = blksum[b] + s[t] - v;   // exclusive
    if (b == 0 && t == 0) rowptr[N_NODES] = E_EDGES;
}

__global__ void k_dinv(const int* __restrict__ cnt, float* __restrict__ dinv) {
    int i = blockIdx.x * blockDim.x + threadIdx.x;
    if (i >= N_NODES) return;
    float deg = (float)(cnt[i] + 1);   // +1 self loop, always > 0
    dinv[i] = rsqrtf(deg);
}

__global__ void k_fill(const int* __restrict__ eidx, const int* __restrict__ rowptr,
                       int* __restrict__ cursor, int* __restrict__ col) {
    int e = blockIdx.x * blockDim.x + threadIdx.x;
    if (e >= E_EDGES) return;
    int srcv = eidx[e];
    int d = eidx[E_EDGES + e];
    int p = rowptr[d] + atomicAdd(&cursor[d], 1);
    col[p] = srcv;
}

// ---------------- layer 1 aggregation (7-wide, fp32 x) ----------------

__global__ void k_agg7(const float* __restrict__ x, const int* __restrict__ rowptr,
                       const int* __restrict__ col, const float* __restrict__ dinv,
                       float* __restrict__ aggx) {
    int i = blockIdx.x * blockDim.x + threadIdx.x;
    if (i >= N_NODES) return;
    float di = dinv[i];
    float a[FIN];
    #pragma unroll
    for (int f = 0; f < FIN; ++f) a[f] = di * x[i * FIN + f];
    int e0 = rowptr[i], e1 = rowptr[i + 1];
    for (int e = e0; e < e1; ++e) {
        int s = col[e];
        float ds = dinv[s];
        #pragma unroll
        for (int f = 0; f < FIN; ++f) a[f] += ds * x[s * FIN + f];
    }
    #pragma unroll
    for (int f = 0; f < FIN; ++f) aggx[i * FIN + f] = di * a[f];
}

// layer-1 matmul: out = relu(aggx @ W1 + b1) cast to packed bf16
__global__ void k_mm1(const float* __restrict__ aggx, const float* __restrict__ W1,
                      const float* __restrict__ b1, unsigned int* __restrict__ g1) {
    int idx = blockIdx.x * blockDim.x + threadIdx.x;   // N*64 threads
    if (idx >= N_NODES * 64) return;
    int n = idx >> 6, fp = idx & 63;
    int f0 = 2 * fp;
    float acc0 = b1[f0], acc1 = b1[f0 + 1];
    #pragma unroll
    for (int k = 0; k < FIN; ++k) {
        float a = aggx[n * FIN + k];
        acc0 += a * W1[k * HID + f0];
        acc1 += a * W1[k * HID + f0 + 1];
    }
    g1[idx] = pack_bf2(fmaxf(acc0, 0.f), fmaxf(acc1, 0.f));
}

// ---------------- 128-wide aggregation (wave per node, bf16 gather) ----------------

__global__ void k_agg128(const unsigned int* __restrict__ g,   // packed bf16 pairs [N][64]
                         float* __restrict__ out,
                         const int* __restrict__ rowptr, const int* __restrict__ col,
                         const float* __restrict__ dinv) {
    int wid = (blockIdx.x * blockDim.x + threadIdx.x) >> 6;
    int lane = threadIdx.x & 63;
    if (wid >= N_NODES) return;
    int i = wid;
    float di = dinv[i];
    unsigned int v = g[i * 64 + lane];
    float ax = di * bf_lo(v), ay = di * bf_hi(v);
    int e0 = rowptr[i], e1 = rowptr[i + 1];
    int e = e0;
    for (; e + 1 < e1; e += 2) {
        int s0 = col[e], s1 = col[e + 1];
        float d0 = dinv[s0], d1 = dinv[s1];
        unsigned int u0 = g[s0 * 64 + lane];
        unsigned int u1 = g[s1 * 64 + lane];
        ax += d0 * bf_lo(u0); ay += d0 * bf_hi(u0);
        ax += d1 * bf_lo(u1); ay += d1 * bf_hi(u1);
    }
    if (e < e1) {
        int s0 = col[e];
        float d0 = dinv[s0];
        unsigned int u0 = g[s0 * 64 + lane];
        ax += d0 * bf_lo(u0); ay += d0 * bf_hi(u0);
    }
    float2 o; o.x = di * ax; o.y = di * ay;
    *(float2*)&out[i * HID + 2 * lane] = o;
}

// ---------------- 128x128 matmul, fp32 acc, register-tiled ----------------
// LAST=false: writes relu(out) as packed bf16 (gather operand for next layer)
// LAST=true : writes fp32, no relu (final h4 for pooling)

template <bool LAST>
__global__ __launch_bounds__(256) void k_mm128(const float* __restrict__ in,
                                               void* __restrict__ outv,
                                               const float* __restrict__ W,
                                               const float* __restrict__ bias) {
    __shared__ float Ws[64 * 128];   // 32 KB (one k-half of W)
    __shared__ float rT[128 * 36];   // 18 KB (32-node tile, k-major, padded)
    int t = threadIdx.x;
    int base = blockIdx.x * 32;

    // stage transposed input tile
    for (int i = t; i < 32 * 128; i += 256) {
        int n = i >> 7, k = i & 127;
        int node = base + n;
        float v = (node < N_NODES) ? in[node * HID + k] : 0.f;
        rT[k * 36 + n] = v;
    }

    int f0 = (t & 31) << 2;   // features f0..f0+3
    int m0 = (t >> 5) << 2;   // nodes m0..m0+3 (within tile)
    float acc[4][4] = {};

    for (int kb = 0; kb < 128; kb += 64) {
        __syncthreads();
        for (int i = t; i < 64 * 128; i += 256)
            Ws[i] = W[(kb + (i >> 7)) * HID + (i & 127)];
        __syncthreads();
        #pragma unroll 4
        for (int kk = 0; kk < 64; ++kk) {
            int k = kb + kk;
            float4 w = *(const float4*)&Ws[kk * 128 + f0];
            float4 r = *(const float4*)&rT[k * 36 + m0];
            acc[0][0] += r.x * w.x; acc[0][1] += r.x * w.y; acc[0][2] += r.x * w.z; acc[0][3] += r.x * w.w;
            acc[1][0] += r.y * w.x; acc[1][1] += r.y * w.y; acc[1][2] += r.y * w.z; acc[1][3] += r.y * w.w;
            acc[2][0] += r.z * w.x; acc[2][1] += r.z * w.y; acc[2][2] += r.z * w.z; acc[2][3] += r.z * w.w;
            acc[3][0] += r.w * w.x; acc[3][1] += r.w * w.y; acc[3][2] += r.w * w.z; acc[3][3] += r.w * w.w;
        }
    }

    float4 bb = *(const float4*)&bias[f0];
    #pragma unroll
    for (int j = 0; j < 4; ++j) {
        int node = base + m0 + j;
        if (node < N_NODES) {
            float o0 = acc[j][0] + bb.x, o1 = acc[j][1] + bb.y;
            float o2 = acc[j][2] + bb.z, o3 = acc[j][3] + bb.w;
            if (LAST) {
                float4 o; o.x = o0; o.y = o1; o.z = o2; o.w = o3;
                *(float4*)&((float*)outv)[node * HID + f0] = o;
            } else {
                uint2 p;
                p.x = pack_bf2(fmaxf(o0, 0.f), fmaxf(o1, 0.f));
                p.y = pack_bf2(fmaxf(o2, 0.f), fmaxf(o3, 0.f));
                *(uint2*)&((unsigned int*)outv)[node * 64 + (f0 >> 1)] = p;
            }
        }
    }
}

// ---------------- pool + linear head ----------------

__global__ void k_pool(const float* __restrict__ h, const int* __restrict__ batch,
                       const float* __restrict__ Wlin, const float* __restrict__ blin,
                       float* __restrict__ out) {
    int wid = (blockIdx.x * blockDim.x + threadIdx.x) >> 6;
    int lane = threadIdx.x & 63;
    if (wid >= NG) return;
    int g = wid;
    int lo = 0, hi = N_NODES;
    while (lo < hi) { int mid = (lo + hi) >> 1; if (batch[mid] < g) lo = mid + 1; else hi = mid; }
    int start = lo;
    hi = N_NODES;
    while (lo < hi) { int mid = (lo + hi) >> 1; if (batch[mid] < g + 1) lo = mid + 1; else hi = mid; }
    int end = lo;

    float sx = 0.f, sy = 0.f;   // features 2*lane, 2*lane+1
    for (int i = start; i < end; ++i) {
        float2 v = *(const float2*)&h[i * HID + 2 * lane];
        sx += v.x; sy += v.y;
    }
    float invc = (end > start) ? 1.0f / (float)(end - start) : 0.f;
    float px = sx * invc, py = sy * invc;

    #pragma unroll
    for (int o = 0; o < 2; ++o) {
        float v = px * Wlin[(2 * lane) * 2 + o] + py * Wlin[(2 * lane + 1) * 2 + o];
        #pragma unroll
        for (int s = 32; s > 0; s >>= 1) v += __shfl_down(v, s);
        if (lane == 0) out[g * 2 + o] = v + blin[o];
    }
}

// ---------------- launcher ----------------

extern "C" void kernel_launch(void* const* d_in, const int* in_sizes, int n_in,
                              void* d_out, int out_size, void* d_ws, size_t ws_size,
                              hipStream_t stream) {
    const float* x    = (const float*)d_in[0];
    const int*   eidx = (const int*)d_in[1];
    const int*   batch= (const int*)d_in[2];
    const float* W1   = (const float*)d_in[3];
    const float* b1   = (const float*)d_in[4];
    const float* W2   = (const float*)d_in[5];
    const float* b2   = (const float*)d_in[6];
    const float* W3   = (const float*)d_in[7];
    const float* b3   = (const float*)d_in[8];
    const float* W4   = (const float*)d_in[9];
    const float* b4   = (const float*)d_in[10];
    const float* Wlin = (const float*)d_in[11];
    const float* blin = (const float*)d_in[12];
    float* out = (float*)d_out;

    // workspace carve-up (256B aligned)
    char* ws = (char*)d_ws;
    size_t off = 0;
    auto carve = [&](size_t bytes) { char* p = ws + off; off = (off + bytes + 255) & ~(size_t)255; return p; };
    int*   cnt    = (int*)carve((size_t)N_NODES * 4);
    int*   rowptr = (int*)carve((size_t)(N_NODES + 1) * 4);
    int*   blksum = (int*)carve((size_t)NB_SCAN * 4);
    float* dinv   = (float*)carve((size_t)N_NODES * 4);
    int*   col    = (int*)carve((size_t)E_EDGES * 4);
    float* aggx   = (float*)carve((size_t)N_NODES * FIN * 4);
    float* aggOut = (float*)carve((size_t)N_NODES * HID * 4);        // fp32 agg result
    char*  gpair  = carve((size_t)N_NODES * HID * 4);                // 2 bf16 g-buffers / final h4
    unsigned int* gA = (unsigned int*)gpair;                          // 25.6 MB
    unsigned int* gB = (unsigned int*)(gpair + (size_t)N_NODES * HID * 2);
    float* h4 = (float*)gpair;   // aliases gA+gB: both dead before mm4 writes
    (void)ws_size; (void)n_in; (void)in_sizes; (void)out_size;

    const int BLK = 256;
    int gridE = (E_EDGES + BLK - 1) / BLK;
    int gridN = (N_NODES + BLK - 1) / BLK;
    int gridAgg = (N_NODES * 64 + BLK - 1) / BLK;   // wave per node
    int gridMM = (N_NODES + 31) / 32;
    int gridMM1 = (N_NODES * 64 + BLK - 1) / BLK;
    int gridPool = (NG * 64 + BLK - 1) / BLK;

    // CSR build
    hipMemsetAsync(cnt, 0, (size_t)N_NODES * 4, stream);
    k_count<<<gridE, BLK, 0, stream>>>(eidx, cnt);
    k_blocksum<<<NB_SCAN, BLK, 0, stream>>>(cnt, blksum);
    k_scan_blk<<<1, 64, 0, stream>>>(blksum);
    k_scan_final<<<NB_SCAN, 1024, 0, stream>>>(cnt, blksum, rowptr);
    k_dinv<<<gridN, BLK, 0, stream>>>(cnt, dinv);
    hipMemsetAsync(cnt, 0, (size_t)N_NODES * 4, stream);   // reuse as cursor
    k_fill<<<gridE, BLK, 0, stream>>>(eidx, rowptr, cnt, col);

    // layer 1: g1 = bf16(relu((A' x) W1 + b1))
    k_agg7<<<gridN, BLK, 0, stream>>>(x, rowptr, col, dinv, aggx);
    k_mm1<<<gridMM1, BLK, 0, stream>>>(aggx, W1, b1, gA);

    // layer 2: g2 = bf16(relu((A' g1) W2 + b2))
    k_agg128<<<gridAgg, BLK, 0, stream>>>(gA, aggOut, rowptr, col, dinv);
    k_mm128<false><<<gridMM, BLK, 0, stream>>>(aggOut, gB, W2, b2);
    // layer 3: g3 = bf16(relu((A' g2) W3 + b3))
    k_agg128<<<gridAgg, BLK, 0, stream>>>(gB, aggOut, rowptr, col, dinv);
    k_mm128<false><<<gridMM, BLK, 0, stream>>>(aggOut, gA, W3, b3);
    // layer 4: h4 = (A' g3) W4 + b4   (fp32, no relu)
    k_agg128<<<gridAgg, BLK, 0, stream>>>(gA, aggOut, rowptr, col, dinv);
    k_mm128<true><<<gridMM, BLK, 0, stream>>>(aggOut, h4, W4, b4);

    // pool + head
    k_pool<<<gridPool, BLK, 0, stream>>>(h4, batch, Wlin, blin, out);
}

// Round 3
// 732.714 us; speedup vs baseline: 1.5286x; 1.2219x over previous
//
#include <hip/hip_runtime.h>
#include <hip/hip_bf16.h>

#define N_NODES 100000
#define E_EDGES 1600000
#define NG 512
#define FIN 7
#define HID 128
#define NBUCK 782          // ceil(N_NODES/128), bucket = 128 consecutive dst nodes
#define CURPAD 16          // pad cursors to separate 64B lines

// bf16 helpers: decode packed pair, encode with RNE
__device__ __forceinline__ float bf_lo(unsigned int u) { return __uint_as_float(u << 16); }
__device__ __forceinline__ float bf_hi(unsigned int u) { return __uint_as_float(u & 0xffff0000u); }
__device__ __forceinline__ unsigned int f2bf_rne(float f) {
    unsigned int x = __float_as_uint(f);
    return (x + 0x7fffu + ((x >> 16) & 1u)) >> 16;   // finite inputs only
}
__device__ __forceinline__ unsigned int pack_bf2(float lo, float hi) {
    return f2bf_rne(lo) | (f2bf_rne(hi) << 16);
}

// ---------------- CSR build (bucketed) ----------------

// Pass A: per-bucket edge histogram (LDS-staged)
__global__ void k_hist(const int* __restrict__ eidx, int* __restrict__ bucketCnt) {
    __shared__ int h[NBUCK];
    int t = threadIdx.x;
    for (int i = t; i < NBUCK; i += 256) h[i] = 0;
    __syncthreads();
    int stride = gridDim.x * blockDim.x;
    for (int e = blockIdx.x * blockDim.x + t; e < E_EDGES; e += stride) {
        int d = eidx[E_EDGES + e];
        atomicAdd(&h[d >> 7], 1);
    }
    __syncthreads();
    for (int i = t; i < NBUCK; i += 256)
        if (h[i]) atomicAdd(&bucketCnt[i], h[i]);
}

// Pass B: exclusive scan of 782 bucket counts (one block)
__global__ void k_scanbuck(const int* __restrict__ bucketCnt, int* __restrict__ bucketBase,
                           int* __restrict__ rowptr) {
    __shared__ int s[1024];
    int t = threadIdx.x;
    int v = (t < NBUCK) ? bucketCnt[t] : 0;
    s[t] = v; __syncthreads();
    for (int st = 1; st < 1024; st <<= 1) {
        int a = (t >= st) ? s[t - st] : 0;
        __syncthreads();
        s[t] += a;
        __syncthreads();
    }
    if (t < NBUCK) bucketBase[t] = s[t] - v;   // exclusive
    if (t == 0) { bucketBase[NBUCK] = E_EDGES; rowptr[N_NODES] = E_EDGES; }
}

// Pass C: scatter packed edge records to bucket-partitioned regions.
// Record: (dst&127)<<17 | src   (src < 2^17)
__global__ void k_scatter(const int* __restrict__ eidx, const int* __restrict__ bucketBase,
                          int* __restrict__ cur, unsigned int* __restrict__ ebuf) {
    int e = blockIdx.x * blockDim.x + threadIdx.x;
    if (e >= E_EDGES) return;
    int s = eidx[e];
    int d = eidx[E_EDGES + e];
    int b = d >> 7;
    int p = bucketBase[b] + atomicAdd(&cur[b * CURPAD], 1);
    ebuf[p] = ((unsigned int)(d & 127) << 17) | (unsigned int)s;
}

// Pass D: per-bucket CSR finalize — counts, scan, rowptr, dinv, col (all LDS-local)
__global__ __launch_bounds__(256) void k_bucket(const unsigned int* __restrict__ ebuf,
                                                const int* __restrict__ bucketBase,
                                                int* __restrict__ rowptr,
                                                float* __restrict__ dinv,
                                                int* __restrict__ col) {
    __shared__ int scnt[128], soff[128], scur[128];
    int b = blockIdx.x, t = threadIdx.x;
    int bbase = bucketBase[b], bend = bucketBase[b + 1];
    if (t < 128) { scnt[t] = 0; scur[t] = 0; }
    __syncthreads();
    // phase 1: per-node counts
    for (int e = bbase + t; e < bend; e += 256) {
        unsigned int rec = ebuf[e];
        atomicAdd(&scnt[rec >> 17], 1);
    }
    __syncthreads();
    // inclusive scan of 128 counts
    if (t < 128) soff[t] = scnt[t];
    __syncthreads();
    for (int st = 1; st < 128; st <<= 1) {
        int a = (t < 128 && t >= st) ? soff[t - st] : 0;
        __syncthreads();
        if (t < 128) soff[t] += a;
        __syncthreads();
    }
    // rowptr + dinv; convert soff to exclusive
    if (t < 128) {
        int ex = soff[t] - scnt[t];
        int node = b * 128 + t;
        if (node < N_NODES) {
            rowptr[node] = bbase + ex;
            dinv[node] = rsqrtf((float)(scnt[t] + 1));   // +1 self-loop
        }
        soff[t] = ex;
    }
    __syncthreads();
    // phase 2: place edges
    for (int e = bbase + t; e < bend; e += 256) {
        unsigned int rec = ebuf[e];
        int dl = rec >> 17;
        int s = rec & 0x1FFFF;
        int p = bbase + soff[dl] + atomicAdd(&scur[dl], 1);
        col[p] = s;
    }
}

// ---------------- layer 1 aggregation (7-wide, fp32 x) ----------------

__global__ void k_agg7(const float* __restrict__ x, const int* __restrict__ rowptr,
                       const int* __restrict__ col, const float* __restrict__ dinv,
                       float* __restrict__ aggx) {
    int i = blockIdx.x * blockDim.x + threadIdx.x;
    if (i >= N_NODES) return;
    float di = dinv[i];
    float a[FIN];
    #pragma unroll
    for (int f = 0; f < FIN; ++f) a[f] = di * x[i * FIN + f];
    int e0 = rowptr[i], e1 = rowptr[i + 1];
    for (int e = e0; e < e1; ++e) {
        int s = col[e];
        float ds = dinv[s];
        #pragma unroll
        for (int f = 0; f < FIN; ++f) a[f] += ds * x[s * FIN + f];
    }
    #pragma unroll
    for (int f = 0; f < FIN; ++f) aggx[i * FIN + f] = di * a[f];
}

// layer-1 matmul: out = relu(aggx @ W1 + b1) cast to packed bf16
__global__ void k_mm1(const float* __restrict__ aggx, const float* __restrict__ W1,
                      const float* __restrict__ b1, unsigned int* __restrict__ g1) {
    int idx = blockIdx.x * blockDim.x + threadIdx.x;   // N*64 threads
    if (idx >= N_NODES * 64) return;
    int n = idx >> 6, fp = idx & 63;
    int f0 = 2 * fp;
    float acc0 = b1[f0], acc1 = b1[f0 + 1];
    #pragma unroll
    for (int k = 0; k < FIN; ++k) {
        float a = aggx[n * FIN + k];
        acc0 += a * W1[k * HID + f0];
        acc1 += a * W1[k * HID + f0 + 1];
    }
    g1[idx] = pack_bf2(fmaxf(acc0, 0.f), fmaxf(acc1, 0.f));
}

// ---------------- 128-wide aggregation (wave/node, bf16 gather, shfl-batched) --------

__global__ void k_agg128(const unsigned int* __restrict__ g,   // packed bf16 pairs [N][64]
                         float* __restrict__ out,
                         const int* __restrict__ rowptr, const int* __restrict__ col,
                         const float* __restrict__ dinv) {
    int wid = (blockIdx.x * blockDim.x + threadIdx.x) >> 6;
    int lane = threadIdx.x & 63;
    if (wid >= N_NODES) return;
    int i = wid;
    float di = dinv[i];
    unsigned int v = g[(size_t)i * 64 + lane];
    float ax = di * bf_lo(v), ay = di * bf_hi(v);
    int e0 = rowptr[i], e1 = rowptr[i + 1];
    for (int base = e0; base < e1; base += 64) {
        int m = e1 - base; if (m > 64) m = 64;
        // cooperative load: 64 cols + dinvs in one coalesced shot
        int sc = 0; float dsv = 0.f;
        if (lane < m) { sc = col[base + lane]; dsv = dinv[sc]; }
        int j = 0;
        for (; j + 3 < m; j += 4) {
            int s0 = __shfl(sc, j),     s1 = __shfl(sc, j + 1);
            int s2 = __shfl(sc, j + 2), s3 = __shfl(sc, j + 3);
            float d0 = __shfl(dsv, j),     d1 = __shfl(dsv, j + 1);
            float d2 = __shfl(dsv, j + 2), d3 = __shfl(dsv, j + 3);
            unsigned int u0 = g[(size_t)s0 * 64 + lane];
            unsigned int u1 = g[(size_t)s1 * 64 + lane];
            unsigned int u2 = g[(size_t)s2 * 64 + lane];
            unsigned int u3 = g[(size_t)s3 * 64 + lane];
            ax += d0 * bf_lo(u0); ay += d0 * bf_hi(u0);
            ax += d1 * bf_lo(u1); ay += d1 * bf_hi(u1);
            ax += d2 * bf_lo(u2); ay += d2 * bf_hi(u2);
            ax += d3 * bf_lo(u3); ay += d3 * bf_hi(u3);
        }
        for (; j < m; ++j) {
            int s0 = __shfl(sc, j);
            float d0 = __shfl(dsv, j);
            unsigned int u0 = g[(size_t)s0 * 64 + lane];
            ax += d0 * bf_lo(u0); ay += d0 * bf_hi(u0);
        }
    }
    float2 o; o.x = di * ax; o.y = di * ay;
    *(float2*)&out[i * HID + 2 * lane] = o;
}

// ---------------- 128x128 matmul, fp32 acc, register-tiled ----------------
// LAST=false: writes relu(out) as packed bf16 (gather operand for next layer)
// LAST=true : writes fp32, no relu (final h4 for pooling)

template <bool LAST>
__global__ __launch_bounds__(256) void k_mm128(const float* __restrict__ in,
                                               void* __restrict__ outv,
                                               const float* __restrict__ W,
                                               const float* __restrict__ bias) {
    __shared__ float Ws[64 * 128];   // 32 KB (one k-half of W)
    __shared__ float rT[128 * 36];   // 18 KB (32-node tile, k-major, padded)
    int t = threadIdx.x;
    int base = blockIdx.x * 32;

    for (int i = t; i < 32 * 128; i += 256) {
        int n = i >> 7, k = i & 127;
        int node = base + n;
        float v = (node < N_NODES) ? in[node * HID + k] : 0.f;
        rT[k * 36 + n] = v;
    }

    int f0 = (t & 31) << 2;   // features f0..f0+3
    int m0 = (t >> 5) << 2;   // nodes m0..m0+3 (within tile)
    float acc[4][4] = {};

    for (int kb = 0; kb < 128; kb += 64) {
        __syncthreads();
        for (int i = t; i < 64 * 128; i += 256)
            Ws[i] = W[(kb + (i >> 7)) * HID + (i & 127)];
        __syncthreads();
        #pragma unroll 4
        for (int kk = 0; kk < 64; ++kk) {
            int k = kb + kk;
            float4 w = *(const float4*)&Ws[kk * 128 + f0];
            float4 r = *(const float4*)&rT[k * 36 + m0];
            acc[0][0] += r.x * w.x; acc[0][1] += r.x * w.y; acc[0][2] += r.x * w.z; acc[0][3] += r.x * w.w;
            acc[1][0] += r.y * w.x; acc[1][1] += r.y * w.y; acc[1][2] += r.y * w.z; acc[1][3] += r.y * w.w;
            acc[2][0] += r.z * w.x; acc[2][1] += r.z * w.y; acc[2][2] += r.z * w.z; acc[2][3] += r.z * w.w;
            acc[3][0] += r.w * w.x; acc[3][1] += r.w * w.y; acc[3][2] += r.w * w.z; acc[3][3] += r.w * w.w;
        }
    }

    float4 bb = *(const float4*)&bias[f0];
    #pragma unroll
    for (int j = 0; j < 4; ++j) {
        int node = base + m0 + j;
        if (node < N_NODES) {
            float o0 = acc[j][0] + bb.x, o1 = acc[j][1] + bb.y;
            float o2 = acc[j][2] + bb.z, o3 = acc[j][3] + bb.w;
            if (LAST) {
                float4 o; o.x = o0; o.y = o1; o.z = o2; o.w = o3;
                *(float4*)&((float*)outv)[node * HID + f0] = o;
            } else {
                uint2 p;
                p.x = pack_bf2(fmaxf(o0, 0.f), fmaxf(o1, 0.f));
                p.y = pack_bf2(fmaxf(o2, 0.f), fmaxf(o3, 0.f));
                *(uint2*)&((unsigned int*)outv)[node * 64 + (f0 >> 1)] = p;
            }
        }
    }
}

// ---------------- pool + linear head ----------------

__global__ void k_pool(const float* __restrict__ h, const int* __restrict__ batch,
                       const float* __restrict__ Wlin, const float* __restrict__ blin,
                       float* __restrict__ out) {
    int wid = (blockIdx.x * blockDim.x + threadIdx.x) >> 6;
    int lane = threadIdx.x & 63;
    if (wid >= NG) return;
    int g = wid;
    int lo = 0, hi = N_NODES;
    while (lo < hi) { int mid = (lo + hi) >> 1; if (batch[mid] < g) lo = mid + 1; else hi = mid; }
    int start = lo;
    hi = N_NODES;
    while (lo < hi) { int mid = (lo + hi) >> 1; if (batch[mid] < g + 1) lo = mid + 1; else hi = mid; }
    int end = lo;

    float sx = 0.f, sy = 0.f;
    for (int i = start; i < end; ++i) {
        float2 v = *(const float2*)&h[i * HID + 2 * lane];
        sx += v.x; sy += v.y;
    }
    float invc = (end > start) ? 1.0f / (float)(end - start) : 0.f;
    float px = sx * invc, py = sy * invc;

    #pragma unroll
    for (int o = 0; o < 2; ++o) {
        float v = px * Wlin[(2 * lane) * 2 + o] + py * Wlin[(2 * lane + 1) * 2 + o];
        #pragma unroll
        for (int s = 32; s > 0; s >>= 1) v += __shfl_down(v, s);
        if (lane == 0) out[g * 2 + o] = v + blin[o];
    }
}

// ---------------- launcher ----------------

extern "C" void kernel_launch(void* const* d_in, const int* in_sizes, int n_in,
                              void* d_out, int out_size, void* d_ws, size_t ws_size,
                              hipStream_t stream) {
    const float* x    = (const float*)d_in[0];
    const int*   eidx = (const int*)d_in[1];
    const int*   batch= (const int*)d_in[2];
    const float* W1   = (const float*)d_in[3];
    const float* b1   = (const float*)d_in[4];
    const float* W2   = (const float*)d_in[5];
    const float* b2   = (const float*)d_in[6];
    const float* W3   = (const float*)d_in[7];
    const float* b3   = (const float*)d_in[8];
    const float* W4   = (const float*)d_in[9];
    const float* b4   = (const float*)d_in[10];
    const float* Wlin = (const float*)d_in[11];
    const float* blin = (const float*)d_in[12];
    float* out = (float*)d_out;

    // workspace carve-up (256B aligned)
    char* ws = (char*)d_ws;
    size_t off = 0;
    auto carve = [&](size_t bytes) { char* p = ws + off; off = (off + bytes + 255) & ~(size_t)255; return p; };
    int*   rowptr    = (int*)carve((size_t)(N_NODES + 1) * 4);
    float* dinv      = (float*)carve((size_t)N_NODES * 4);
    int*   col       = (int*)carve((size_t)E_EDGES * 4);
    unsigned int* ebuf = (unsigned int*)carve((size_t)E_EDGES * 4);
    int*   bucketCnt = (int*)carve((size_t)NBUCK * 4);
    int*   bucketBase= (int*)carve((size_t)(NBUCK + 1) * 4);
    int*   cur       = (int*)carve((size_t)NBUCK * CURPAD * 4);
    float* aggx      = (float*)carve((size_t)N_NODES * FIN * 4);
    float* aggOut    = (float*)carve((size_t)N_NODES * HID * 4);
    char*  gpair     = carve((size_t)N_NODES * HID * 4);   // 2 bf16 g-buffers / final h4
    unsigned int* gA = (unsigned int*)gpair;
    unsigned int* gB = (unsigned int*)(gpair + (size_t)N_NODES * HID * 2);
    float* h4 = (float*)gpair;   // aliases gA+gB: both dead before mm4 writes
    (void)ws_size; (void)n_in; (void)in_sizes; (void)out_size;

    const int BLK = 256;
    int gridE = (E_EDGES + BLK - 1) / BLK;
    int gridN = (N_NODES + BLK - 1) / BLK;
    int gridAgg = (N_NODES * 64 + BLK - 1) / BLK;
    int gridMM = (N_NODES + 31) / 32;
    int gridMM1 = (N_NODES * 64 + BLK - 1) / BLK;
    int gridPool = (NG * 64 + BLK - 1) / BLK;

    // CSR build (bucketed)
    hipMemsetAsync(bucketCnt, 0, (size_t)NBUCK * 4, stream);
    hipMemsetAsync(cur, 0, (size_t)NBUCK * CURPAD * 4, stream);
    k_hist<<<128, BLK, 0, stream>>>(eidx, bucketCnt);
    k_scanbuck<<<1, 1024, 0, stream>>>(bucketCnt, bucketBase, rowptr);
    k_scatter<<<gridE, BLK, 0, stream>>>(eidx, bucketBase, cur, ebuf);
    k_bucket<<<NBUCK, BLK, 0, stream>>>(ebuf, bucketBase, rowptr, dinv, col);

    // layer 1: g1 = bf16(relu((A' x) W1 + b1))
    k_agg7<<<gridN, BLK, 0, stream>>>(x, rowptr, col, dinv, aggx);
    k_mm1<<<gridMM1, BLK, 0, stream>>>(aggx, W1, b1, gA);

    // layer 2: g2 = bf16(relu((A' g1) W2 + b2))
    k_agg128<<<gridAgg, BLK, 0, stream>>>(gA, aggOut, rowptr, col, dinv);
    k_mm128<false><<<gridMM, BLK, 0, stream>>>(aggOut, gB, W2, b2);
    // layer 3: g3 = bf16(relu((A' g2) W3 + b3))
    k_agg128<<<gridAgg, BLK, 0, stream>>>(gB, aggOut, rowptr, col, dinv);
    k_mm128<false><<<gridMM, BLK, 0, stream>>>(aggOut, gA, W3, b3);
    // layer 4: h4 = (A' g3) W4 + b4   (fp32, no relu)
    k_agg128<<<gridAgg, BLK, 0, stream>>>(gA, aggOut, rowptr, col, dinv);
    k_mm128<true><<<gridMM, BLK, 0, stream>>>(aggOut, h4, W4, b4);

    // pool + head
    k_pool<<<gridPool, BLK, 0, stream>>>(h4, batch, Wlin, blin, out);
}

// Round 4
// 677.315 us; speedup vs baseline: 1.6536x; 1.0818x over previous
//
#include <hip/hip_runtime.h>
#include <hip/hip_bf16.h>

#define N_NODES 100000
#define E_EDGES 1600000
#define NG 512
#define FIN 7
#define HID 128
#define NBUCK 782          // ceil(N_NODES/128), bucket = 128 consecutive dst nodes
#define NBLK_SC 128        // partition blocks (each owns a contiguous edge chunk)
#define CHUNK 12500        // E_EDGES / NBLK_SC (exact)
#define TLEN (NBUCK * NBLK_SC)   // 100096 table entries
#define NCH 98             // ceil(TLEN/1024) scan chunks

// bf16 helpers: decode packed pair, encode with RNE
__device__ __forceinline__ float bf_lo(unsigned int u) { return __uint_as_float(u << 16); }
__device__ __forceinline__ float bf_hi(unsigned int u) { return __uint_as_float(u & 0xffff0000u); }
__device__ __forceinline__ unsigned int f2bf_rne(float f) {
    unsigned int x = __float_as_uint(f);
    return (x + 0x7fffu + ((x >> 16) & 1u)) >> 16;   // finite inputs only
}
__device__ __forceinline__ unsigned int pack_bf2(float lo, float hi) {
    return f2bf_rne(lo) | (f2bf_rne(hi) << 16);
}

// ---------------- CSR build (radix partition) ----------------

// Pass 1: per-(bucket, block) histogram. table[bin*NBLK_SC + blk]
__global__ __launch_bounds__(256) void k_hist2(const int* __restrict__ eidx,
                                               int* __restrict__ table) {
    __shared__ int h[NBUCK];
    int blk = blockIdx.x, t = threadIdx.x;
    for (int i = t; i < NBUCK; i += 256) h[i] = 0;
    __syncthreads();
    int e0 = blk * CHUNK, e1 = e0 + CHUNK;
    for (int e = e0 + t; e < e1; e += 256)
        atomicAdd(&h[eidx[E_EDGES + e] >> 7], 1);
    __syncthreads();
    for (int i = t; i < NBUCK; i += 256)
        table[i * NBLK_SC + blk] = h[i];
}

// Scan step 1: 1024-chunk sums
__global__ void k_blocksum(const int* __restrict__ table, int* __restrict__ partial) {
    __shared__ int s[256];
    int b = blockIdx.x, t = threadIdx.x;
    int base = b * 1024;
    int sum = 0;
    for (int i = t; i < 1024; i += 256) {
        int idx = base + i;
        sum += (idx < TLEN) ? table[idx] : 0;
    }
    s[t] = sum; __syncthreads();
    for (int st = 128; st > 0; st >>= 1) {
        if (t < st) s[t] += s[t + st];
        __syncthreads();
    }
    if (t == 0) partial[b] = s[0];
}

// Scan step 2: serial exclusive scan of chunk sums
__global__ void k_scan_blk(int* __restrict__ partial) {
    if (threadIdx.x == 0 && blockIdx.x == 0) {
        int run = 0;
        for (int i = 0; i < NCH; ++i) { int v = partial[i]; partial[i] = run; run += v; }
    }
}

// Scan step 3: in-place exclusive scan of table
__global__ void k_scan_final(int* __restrict__ table, const int* __restrict__ partial) {
    __shared__ int s[1024];
    int b = blockIdx.x, t = threadIdx.x;
    int idx = b * 1024 + t;
    int v = (idx < TLEN) ? table[idx] : 0;
    s[t] = v; __syncthreads();
    for (int st = 1; st < 1024; st <<= 1) {
        int add = (t >= st) ? s[t - st] : 0;
        __syncthreads();
        s[t] += add;
        __syncthreads();
    }
    if (idx < TLEN) table[idx] = partial[b] + s[t] - v;   // exclusive
}

// Extract per-bucket bases
__global__ void k_bbase(const int* __restrict__ table, int* __restrict__ bucketBase,
                        int* __restrict__ rowptr) {
    int t = blockIdx.x * blockDim.x + threadIdx.x;
    if (t < NBUCK) bucketBase[t] = table[t * NBLK_SC];
    if (t == 0) { bucketBase[NBUCK] = E_EDGES; rowptr[N_NODES] = E_EDGES; }
}

// Pass 2: partition scatter — each block writes its chunk's edges into its
// private contiguous per-bucket ranges. Record: (dst&127)<<17 | src
__global__ __launch_bounds__(256) void k_scatter2(const int* __restrict__ eidx,
                                                  const int* __restrict__ table,
                                                  unsigned int* __restrict__ ebuf) {
    __shared__ int loff[NBUCK];
    int blk = blockIdx.x, t = threadIdx.x;
    for (int i = t; i < NBUCK; i += 256) loff[i] = table[i * NBLK_SC + blk];
    __syncthreads();
    int e0 = blk * CHUNK, e1 = e0 + CHUNK;
    for (int e = e0 + t; e < e1; e += 256) {
        int s = eidx[e];
        int d = eidx[E_EDGES + e];
        int p = atomicAdd(&loff[d >> 7], 1);
        ebuf[p] = ((unsigned int)(d & 127) << 17) | (unsigned int)s;
    }
}

// Per-bucket CSR finalize — counts, scan, rowptr, dinv, col (all LDS-local)
__global__ __launch_bounds__(256) void k_bucket(const unsigned int* __restrict__ ebuf,
                                                const int* __restrict__ bucketBase,
                                                int* __restrict__ rowptr,
                                                float* __restrict__ dinv,
                                                int* __restrict__ col) {
    __shared__ int scnt[128], soff[128], scur[128];
    int b = blockIdx.x, t = threadIdx.x;
    int bbase = bucketBase[b], bend = bucketBase[b + 1];
    if (t < 128) { scnt[t] = 0; scur[t] = 0; }
    __syncthreads();
    for (int e = bbase + t; e < bend; e += 256) {
        unsigned int rec = ebuf[e];
        atomicAdd(&scnt[rec >> 17], 1);
    }
    __syncthreads();
    if (t < 128) soff[t] = scnt[t];
    __syncthreads();
    for (int st = 1; st < 128; st <<= 1) {
        int a = (t < 128 && t >= st) ? soff[t - st] : 0;
        __syncthreads();
        if (t < 128) soff[t] += a;
        __syncthreads();
    }
    if (t < 128) {
        int ex = soff[t] - scnt[t];
        int node = b * 128 + t;
        if (node < N_NODES) {
            rowptr[node] = bbase + ex;
            dinv[node] = rsqrtf((float)(scnt[t] + 1));   // +1 self-loop
        }
        soff[t] = ex;
    }
    __syncthreads();
    for (int e = bbase + t; e < bend; e += 256) {
        unsigned int rec = ebuf[e];
        int dl = rec >> 17;
        int s = rec & 0x1FFFF;
        int p = bbase + soff[dl] + atomicAdd(&scur[dl], 1);
        col[p] = s;
    }
}

// ---------------- layer 1 aggregation (7-wide, fp32 x) ----------------

__global__ void k_agg7(const float* __restrict__ x, const int* __restrict__ rowptr,
                       const int* __restrict__ col, const float* __restrict__ dinv,
                       float* __restrict__ aggx) {
    int i = blockIdx.x * blockDim.x + threadIdx.x;
    if (i >= N_NODES) return;
    float di = dinv[i];
    float a[FIN];
    #pragma unroll
    for (int f = 0; f < FIN; ++f) a[f] = di * x[i * FIN + f];
    int e0 = rowptr[i], e1 = rowptr[i + 1];
    for (int e = e0; e < e1; ++e) {
        int s = col[e];
        float ds = dinv[s];
        #pragma unroll
        for (int f = 0; f < FIN; ++f) a[f] += ds * x[s * FIN + f];
    }
    #pragma unroll
    for (int f = 0; f < FIN; ++f) aggx[i * FIN + f] = di * a[f];
}

// layer-1 matmul: out = relu(aggx @ W1 + b1) cast to packed bf16
__global__ void k_mm1(const float* __restrict__ aggx, const float* __restrict__ W1,
                      const float* __restrict__ b1, unsigned int* __restrict__ g1) {
    int idx = blockIdx.x * blockDim.x + threadIdx.x;   // N*64 threads
    if (idx >= N_NODES * 64) return;
    int n = idx >> 6, fp = idx & 63;
    int f0 = 2 * fp;
    float acc0 = b1[f0], acc1 = b1[f0 + 1];
    #pragma unroll
    for (int k = 0; k < FIN; ++k) {
        float a = aggx[n * FIN + k];
        acc0 += a * W1[k * HID + f0];
        acc1 += a * W1[k * HID + f0 + 1];
    }
    g1[idx] = pack_bf2(fmaxf(acc0, 0.f), fmaxf(acc1, 0.f));
}

// ---------------- 128-wide aggregation (wave/node, bf16 gather, shfl-batched) --------

__global__ void k_agg128(const unsigned int* __restrict__ g,   // packed bf16 pairs [N][64]
                         float* __restrict__ out,
                         const int* __restrict__ rowptr, const int* __restrict__ col,
                         const float* __restrict__ dinv) {
    int wid = (blockIdx.x * blockDim.x + threadIdx.x) >> 6;
    int lane = threadIdx.x & 63;
    if (wid >= N_NODES) return;
    int i = wid;
    float di = dinv[i];
    unsigned int v = g[(size_t)i * 64 + lane];
    float ax = di * bf_lo(v), ay = di * bf_hi(v);
    int e0 = rowptr[i], e1 = rowptr[i + 1];
    for (int base = e0; base < e1; base += 64) {
        int m = e1 - base; if (m > 64) m = 64;
        int sc = 0; float dsv = 0.f;
        if (lane < m) { sc = col[base + lane]; dsv = dinv[sc]; }
        int j = 0;
        for (; j + 3 < m; j += 4) {
            int s0 = __shfl(sc, j),     s1 = __shfl(sc, j + 1);
            int s2 = __shfl(sc, j + 2), s3 = __shfl(sc, j + 3);
            float d0 = __shfl(dsv, j),     d1 = __shfl(dsv, j + 1);
            float d2 = __shfl(dsv, j + 2), d3 = __shfl(dsv, j + 3);
            unsigned int u0 = g[(size_t)s0 * 64 + lane];
            unsigned int u1 = g[(size_t)s1 * 64 + lane];
            unsigned int u2 = g[(size_t)s2 * 64 + lane];
            unsigned int u3 = g[(size_t)s3 * 64 + lane];
            ax += d0 * bf_lo(u0); ay += d0 * bf_hi(u0);
            ax += d1 * bf_lo(u1); ay += d1 * bf_hi(u1);
            ax += d2 * bf_lo(u2); ay += d2 * bf_hi(u2);
            ax += d3 * bf_lo(u3); ay += d3 * bf_hi(u3);
        }
        for (; j < m; ++j) {
            int s0 = __shfl(sc, j);
            float d0 = __shfl(dsv, j);
            unsigned int u0 = g[(size_t)s0 * 64 + lane];
            ax += d0 * bf_lo(u0); ay += d0 * bf_hi(u0);
        }
    }
    float2 o; o.x = di * ax; o.y = di * ay;
    *(float2*)&out[i * HID + 2 * lane] = o;
}

// ---------------- 128x128 matmul, fp32 acc, register-tiled ----------------

template <bool LAST>
__global__ __launch_bounds__(256) void k_mm128(const float* __restrict__ in,
                                               void* __restrict__ outv,
                                               const float* __restrict__ W,
                                               const float* __restrict__ bias) {
    __shared__ float Ws[64 * 128];   // 32 KB
    __shared__ float rT[128 * 36];   // 18 KB
    int t = threadIdx.x;
    int base = blockIdx.x * 32;

    for (int i = t; i < 32 * 128; i += 256) {
        int n = i >> 7, k = i & 127;
        int node = base + n;
        float v = (node < N_NODES) ? in[node * HID + k] : 0.f;
        rT[k * 36 + n] = v;
    }

    int f0 = (t & 31) << 2;
    int m0 = (t >> 5) << 2;
    float acc[4][4] = {};

    for (int kb = 0; kb < 128; kb += 64) {
        __syncthreads();
        for (int i = t; i < 64 * 128; i += 256)
            Ws[i] = W[(kb + (i >> 7)) * HID + (i & 127)];
        __syncthreads();
        #pragma unroll 4
        for (int kk = 0; kk < 64; ++kk) {
            int k = kb + kk;
            float4 w = *(const float4*)&Ws[kk * 128 + f0];
            float4 r = *(const float4*)&rT[k * 36 + m0];
            acc[0][0] += r.x * w.x; acc[0][1] += r.x * w.y; acc[0][2] += r.x * w.z; acc[0][3] += r.x * w.w;
            acc[1][0] += r.y * w.x; acc[1][1] += r.y * w.y; acc[1][2] += r.y * w.z; acc[1][3] += r.y * w.w;
            acc[2][0] += r.z * w.x; acc[2][1] += r.z * w.y; acc[2][2] += r.z * w.z; acc[2][3] += r.z * w.w;
            acc[3][0] += r.w * w.x; acc[3][1] += r.w * w.y; acc[3][2] += r.w * w.z; acc[3][3] += r.w * w.w;
        }
    }

    float4 bb = *(const float4*)&bias[f0];
    #pragma unroll
    for (int j = 0; j < 4; ++j) {
        int node = base + m0 + j;
        if (node < N_NODES) {
            float o0 = acc[j][0] + bb.x, o1 = acc[j][1] + bb.y;
            float o2 = acc[j][2] + bb.z, o3 = acc[j][3] + bb.w;
            if (LAST) {
                float4 o; o.x = o0; o.y = o1; o.z = o2; o.w = o3;
                *(float4*)&((float*)outv)[node * HID + f0] = o;
            } else {
                uint2 p;
                p.x = pack_bf2(fmaxf(o0, 0.f), fmaxf(o1, 0.f));
                p.y = pack_bf2(fmaxf(o2, 0.f), fmaxf(o3, 0.f));
                *(uint2*)&((unsigned int*)outv)[node * 64 + (f0 >> 1)] = p;
            }
        }
    }
}

// ---------------- pool + linear head ----------------

__global__ void k_pool(const float* __restrict__ h, const int* __restrict__ batch,
                       const float* __restrict__ Wlin, const float* __restrict__ blin,
                       float* __restrict__ out) {
    int wid = (blockIdx.x * blockDim.x + threadIdx.x) >> 6;
    int lane = threadIdx.x & 63;
    if (wid >= NG) return;
    int g = wid;
    int lo = 0, hi = N_NODES;
    while (lo < hi) { int mid = (lo + hi) >> 1; if (batch[mid] < g) lo = mid + 1; else hi = mid; }
    int start = lo;
    hi = N_NODES;
    while (lo < hi) { int mid = (lo + hi) >> 1; if (batch[mid] < g + 1) lo = mid + 1; else hi = mid; }
    int end = lo;

    float sx = 0.f, sy = 0.f;
    for (int i = start; i < end; ++i) {
        float2 v = *(const float2*)&h[i * HID + 2 * lane];
        sx += v.x; sy += v.y;
    }
    float invc = (end > start) ? 1.0f / (float)(end - start) : 0.f;
    float px = sx * invc, py = sy * invc;

    #pragma unroll
    for (int o = 0; o < 2; ++o) {
        float v = px * Wlin[(2 * lane) * 2 + o] + py * Wlin[(2 * lane + 1) * 2 + o];
        #pragma unroll
        for (int s = 32; s > 0; s >>= 1) v += __shfl_down(v, s);
        if (lane == 0) out[g * 2 + o] = v + blin[o];
    }
}

// ---------------- launcher ----------------

extern "C" void kernel_launch(void* const* d_in, const int* in_sizes, int n_in,
                              void* d_out, int out_size, void* d_ws, size_t ws_size,
                              hipStream_t stream) {
    const float* x    = (const float*)d_in[0];
    const int*   eidx = (const int*)d_in[1];
    const int*   batch= (const int*)d_in[2];
    const float* W1   = (const float*)d_in[3];
    const float* b1   = (const float*)d_in[4];
    const float* W2   = (const float*)d_in[5];
    const float* b2   = (const float*)d_in[6];
    const float* W3   = (const float*)d_in[7];
    const float* b3   = (const float*)d_in[8];
    const float* W4   = (const float*)d_in[9];
    const float* b4   = (const float*)d_in[10];
    const float* Wlin = (const float*)d_in[11];
    const float* blin = (const float*)d_in[12];
    float* out = (float*)d_out;

    // workspace carve-up (256B aligned)
    char* ws = (char*)d_ws;
    size_t off = 0;
    auto carve = [&](size_t bytes) { char* p = ws + off; off = (off + bytes + 255) & ~(size_t)255; return p; };
    int*   rowptr    = (int*)carve((size_t)(N_NODES + 1) * 4);
    float* dinv      = (float*)carve((size_t)N_NODES * 4);
    int*   col       = (int*)carve((size_t)E_EDGES * 4);
    unsigned int* ebuf = (unsigned int*)carve((size_t)E_EDGES * 4);
    int*   table     = (int*)carve((size_t)TLEN * 4);
    int*   partial   = (int*)carve((size_t)NCH * 4);
    int*   bucketBase= (int*)carve((size_t)(NBUCK + 1) * 4);
    float* aggx      = (float*)carve((size_t)N_NODES * FIN * 4);
    float* aggOut    = (float*)carve((size_t)N_NODES * HID * 4);
    char*  gpair     = carve((size_t)N_NODES * HID * 4);   // 2 bf16 g-buffers / final h4
    unsigned int* gA = (unsigned int*)gpair;
    unsigned int* gB = (unsigned int*)(gpair + (size_t)N_NODES * HID * 2);
    float* h4 = (float*)gpair;   // aliases gA+gB: both dead before mm4 writes
    (void)ws_size; (void)n_in; (void)in_sizes; (void)out_size;

    const int BLK = 256;
    int gridN = (N_NODES + BLK - 1) / BLK;
    int gridAgg = (N_NODES * 64 + BLK - 1) / BLK;
    int gridMM = (N_NODES + 31) / 32;
    int gridMM1 = (N_NODES * 64 + BLK - 1) / BLK;
    int gridPool = (NG * 64 + BLK - 1) / BLK;

    // CSR build (radix partition: hist -> scan -> scatter -> bucket finalize)
    k_hist2<<<NBLK_SC, BLK, 0, stream>>>(eidx, table);
    k_blocksum<<<NCH, BLK, 0, stream>>>(table, partial);
    k_scan_blk<<<1, 64, 0, stream>>>(partial);
    k_scan_final<<<NCH, 1024, 0, stream>>>(table, partial);
    k_bbase<<<1, 1024, 0, stream>>>(table, bucketBase, rowptr);
    k_scatter2<<<NBLK_SC, BLK, 0, stream>>>(eidx, table, ebuf);
    k_bucket<<<NBUCK, BLK, 0, stream>>>(ebuf, bucketBase, rowptr, dinv, col);

    // layer 1: g1 = bf16(relu((A' x) W1 + b1))
    k_agg7<<<gridN, BLK, 0, stream>>>(x, rowptr, col, dinv, aggx);
    k_mm1<<<gridMM1, BLK, 0, stream>>>(aggx, W1, b1, gA);

    // layer 2: g2 = bf16(relu((A' g1) W2 + b2))
    k_agg128<<<gridAgg, BLK, 0, stream>>>(gA, aggOut, rowptr, col, dinv);
    k_mm128<false><<<gridMM, BLK, 0, stream>>>(aggOut, gB, W2, b2);
    // layer 3
    k_agg128<<<gridAgg, BLK, 0, stream>>>(gB, aggOut, rowptr, col, dinv);
    k_mm128<false><<<gridMM, BLK, 0, stream>>>(aggOut, gA, W3, b3);
    // layer 4 (fp32, no relu)
    k_agg128<<<gridAgg, BLK, 0, stream>>>(gA, aggOut, rowptr, col, dinv);
    k_mm128<true><<<gridMM, BLK, 0, stream>>>(aggOut, h4, W4, b4);

    // pool + head
    k_pool<<<gridPool, BLK, 0, stream>>>(h4, batch, Wlin, blin, out);
}

// Round 5
// 568.727 us; speedup vs baseline: 1.9693x; 1.1909x over previous
//
#include <hip/hip_runtime.h>
#include <hip/hip_bf16.h>

#define N_NODES 100000
#define E_EDGES 1600000
#define NG 512
#define FIN 7
#define HID 128
#define NBUCK 782          // ceil(N_NODES/128), bucket = 128 consecutive dst nodes
#define NBLK_SC 128        // partition blocks (each owns a contiguous edge chunk)
#define CHUNK 12500        // E_EDGES / NBLK_SC (exact)
#define TLEN (NBUCK * NBLK_SC)   // 100096 table entries
#define NCH 98             // ceil(TLEN/1024) scan chunks

// bf16 helpers: decode packed pair, encode with RNE
__device__ __forceinline__ float bf_lo(unsigned int u) { return __uint_as_float(u << 16); }
__device__ __forceinline__ float bf_hi(unsigned int u) { return __uint_as_float(u & 0xffff0000u); }
__device__ __forceinline__ unsigned int f2bf_rne(float f) {
    unsigned int x = __float_as_uint(f);
    return (x + 0x7fffu + ((x >> 16) & 1u)) >> 16;   // finite inputs only
}
__device__ __forceinline__ unsigned int pack_bf2(float lo, float hi) {
    return f2bf_rne(lo) | (f2bf_rne(hi) << 16);
}

// ---------------- CSR build (radix partition) ----------------

__global__ __launch_bounds__(256) void k_hist2(const int* __restrict__ eidx,
                                               int* __restrict__ table) {
    __shared__ int h[NBUCK];
    int blk = blockIdx.x, t = threadIdx.x;
    for (int i = t; i < NBUCK; i += 256) h[i] = 0;
    __syncthreads();
    int e0 = blk * CHUNK, e1 = e0 + CHUNK;
    for (int e = e0 + t; e < e1; e += 256)
        atomicAdd(&h[eidx[E_EDGES + e] >> 7], 1);
    __syncthreads();
    for (int i = t; i < NBUCK; i += 256)
        table[i * NBLK_SC + blk] = h[i];
}

__global__ void k_blocksum(const int* __restrict__ table, int* __restrict__ partial) {
    __shared__ int s[256];
    int b = blockIdx.x, t = threadIdx.x;
    int base = b * 1024;
    int sum = 0;
    for (int i = t; i < 1024; i += 256) {
        int idx = base + i;
        sum += (idx < TLEN) ? table[idx] : 0;
    }
    s[t] = sum; __syncthreads();
    for (int st = 128; st > 0; st >>= 1) {
        if (t < st) s[t] += s[t + st];
        __syncthreads();
    }
    if (t == 0) partial[b] = s[0];
}

__global__ void k_scan_blk(int* __restrict__ partial) {
    if (threadIdx.x == 0 && blockIdx.x == 0) {
        int run = 0;
        for (int i = 0; i < NCH; ++i) { int v = partial[i]; partial[i] = run; run += v; }
    }
}

__global__ void k_scan_final(int* __restrict__ table, const int* __restrict__ partial) {
    __shared__ int s[1024];
    int b = blockIdx.x, t = threadIdx.x;
    int idx = b * 1024 + t;
    int v = (idx < TLEN) ? table[idx] : 0;
    s[t] = v; __syncthreads();
    for (int st = 1; st < 1024; st <<= 1) {
        int add = (t >= st) ? s[t - st] : 0;
        __syncthreads();
        s[t] += add;
        __syncthreads();
    }
    if (idx < TLEN) table[idx] = partial[b] + s[t] - v;   // exclusive
}

__global__ void k_bbase(const int* __restrict__ table, int* __restrict__ bucketBase,
                        int* __restrict__ rowptr) {
    int t = blockIdx.x * blockDim.x + threadIdx.x;
    if (t < NBUCK) bucketBase[t] = table[t * NBLK_SC];
    if (t == 0) { bucketBase[NBUCK] = E_EDGES; rowptr[N_NODES] = E_EDGES; }
}

__global__ __launch_bounds__(256) void k_scatter2(const int* __restrict__ eidx,
                                                  const int* __restrict__ table,
                                                  unsigned int* __restrict__ ebuf) {
    __shared__ int loff[NBUCK];
    int blk = blockIdx.x, t = threadIdx.x;
    for (int i = t; i < NBUCK; i += 256) loff[i] = table[i * NBLK_SC + blk];
    __syncthreads();
    int e0 = blk * CHUNK, e1 = e0 + CHUNK;
    for (int e = e0 + t; e < e1; e += 256) {
        int s = eidx[e];
        int d = eidx[E_EDGES + e];
        int p = atomicAdd(&loff[d >> 7], 1);
        ebuf[p] = ((unsigned int)(d & 127) << 17) | (unsigned int)s;
    }
}

__global__ __launch_bounds__(256) void k_bucket(const unsigned int* __restrict__ ebuf,
                                                const int* __restrict__ bucketBase,
                                                int* __restrict__ rowptr,
                                                float* __restrict__ dinv,
                                                int* __restrict__ col) {
    __shared__ int scnt[128], soff[128], scur[128];
    int b = blockIdx.x, t = threadIdx.x;
    int bbase = bucketBase[b], bend = bucketBase[b + 1];
    if (t < 128) { scnt[t] = 0; scur[t] = 0; }
    __syncthreads();
    for (int e = bbase + t; e < bend; e += 256) {
        unsigned int rec = ebuf[e];
        atomicAdd(&scnt[rec >> 17], 1);
    }
    __syncthreads();
    if (t < 128) soff[t] = scnt[t];
    __syncthreads();
    for (int st = 1; st < 128; st <<= 1) {
        int a = (t < 128 && t >= st) ? soff[t - st] : 0;
        __syncthreads();
        if (t < 128) soff[t] += a;
        __syncthreads();
    }
    if (t < 128) {
        int ex = soff[t] - scnt[t];
        int node = b * 128 + t;
        if (node < N_NODES) {
            rowptr[node] = bbase + ex;
            dinv[node] = rsqrtf((float)(scnt[t] + 1));   // +1 self-loop
        }
        soff[t] = ex;
    }
    __syncthreads();
    for (int e = bbase + t; e < bend; e += 256) {
        unsigned int rec = ebuf[e];
        int dl = rec >> 17;
        int s = rec & 0x1FFFF;
        int p = bbase + soff[dl] + atomicAdd(&scur[dl], 1);
        col[p] = s;
    }
}

// ---------------- layer 1 aggregation (7-wide, fp32 x) ----------------

__global__ void k_agg7(const float* __restrict__ x, const int* __restrict__ rowptr,
                       const int* __restrict__ col, const float* __restrict__ dinv,
                       float* __restrict__ aggx) {
    int i = blockIdx.x * blockDim.x + threadIdx.x;
    if (i >= N_NODES) return;
    float di = dinv[i];
    float a[FIN];
    #pragma unroll
    for (int f = 0; f < FIN; ++f) a[f] = di * x[i * FIN + f];
    int e0 = rowptr[i], e1 = rowptr[i + 1];
    for (int e = e0; e < e1; ++e) {
        int s = col[e];
        float ds = dinv[s];
        #pragma unroll
        for (int f = 0; f < FIN; ++f) a[f] += ds * x[s * FIN + f];
    }
    #pragma unroll
    for (int f = 0; f < FIN; ++f) aggx[i * FIN + f] = di * a[f];
}

// layer-1 matmul: out = relu(aggx @ W1 + b1) cast to packed bf16
__global__ void k_mm1(const float* __restrict__ aggx, const float* __restrict__ W1,
                      const float* __restrict__ b1, unsigned int* __restrict__ g1) {
    int idx = blockIdx.x * blockDim.x + threadIdx.x;   // N*64 threads
    if (idx >= N_NODES * 64) return;
    int n = idx >> 6, fp = idx & 63;
    int f0 = 2 * fp;
    float acc0 = b1[f0], acc1 = b1[f0 + 1];
    #pragma unroll
    for (int k = 0; k < FIN; ++k) {
        float a = aggx[n * FIN + k];
        acc0 += a * W1[k * HID + f0];
        acc1 += a * W1[k * HID + f0 + 1];
    }
    g1[idx] = pack_bf2(fmaxf(acc0, 0.f), fmaxf(acc1, 0.f));
}

// ---------------- 128-wide aggregation (wave/node, bf16 gather, shfl-batched) --------

__global__ void k_agg128(const unsigned int* __restrict__ g,   // packed bf16 pairs [N][64]
                         float* __restrict__ out,
                         const int* __restrict__ rowptr, const int* __restrict__ col,
                         const float* __restrict__ dinv) {
    int wid = (blockIdx.x * blockDim.x + threadIdx.x) >> 6;
    int lane = threadIdx.x & 63;
    if (wid >= N_NODES) return;
    int i = wid;
    float di = dinv[i];
    unsigned int v = g[(size_t)i * 64 + lane];
    float ax = di * bf_lo(v), ay = di * bf_hi(v);
    int e0 = rowptr[i], e1 = rowptr[i + 1];
    for (int base = e0; base < e1; base += 64) {
        int m = e1 - base; if (m > 64) m = 64;
        int sc = 0; float dsv = 0.f;
        if (lane < m) { sc = col[base + lane]; dsv = dinv[sc]; }
        int j = 0;
        for (; j + 3 < m; j += 4) {
            int s0 = __shfl(sc, j),     s1 = __shfl(sc, j + 1);
            int s2 = __shfl(sc, j + 2), s3 = __shfl(sc, j + 3);
            float d0 = __shfl(dsv, j),     d1 = __shfl(dsv, j + 1);
            float d2 = __shfl(dsv, j + 2), d3 = __shfl(dsv, j + 3);
            unsigned int u0 = g[(size_t)s0 * 64 + lane];
            unsigned int u1 = g[(size_t)s1 * 64 + lane];
            unsigned int u2 = g[(size_t)s2 * 64 + lane];
            unsigned int u3 = g[(size_t)s3 * 64 + lane];
            ax += d0 * bf_lo(u0); ay += d0 * bf_hi(u0);
            ax += d1 * bf_lo(u1); ay += d1 * bf_hi(u1);
            ax += d2 * bf_lo(u2); ay += d2 * bf_hi(u2);
            ax += d3 * bf_lo(u3); ay += d3 * bf_hi(u3);
        }
        for (; j < m; ++j) {
            int s0 = __shfl(sc, j);
            float d0 = __shfl(dsv, j);
            unsigned int u0 = g[(size_t)s0 * 64 + lane];
            ax += d0 * bf_lo(u0); ay += d0 * bf_hi(u0);
        }
    }
    float2 o; o.x = di * ax; o.y = di * ay;
    *(float2*)&out[i * HID + 2 * lane] = o;
}

// ---------------- 128x128 matmul, fp32 acc, register-tiled (layers 2,3) --------------

__global__ __launch_bounds__(256) void k_mm128(const float* __restrict__ in,
                                               unsigned int* __restrict__ outg,
                                               const float* __restrict__ W,
                                               const float* __restrict__ bias) {
    __shared__ float Ws[64 * 128];   // 32 KB
    __shared__ float rT[128 * 36];   // 18 KB
    int t = threadIdx.x;
    int base = blockIdx.x * 32;

    for (int i = t; i < 32 * 128; i += 256) {
        int n = i >> 7, k = i & 127;
        int node = base + n;
        float v = (node < N_NODES) ? in[node * HID + k] : 0.f;
        rT[k * 36 + n] = v;
    }

    int f0 = (t & 31) << 2;
    int m0 = (t >> 5) << 2;
    float acc[4][4] = {};

    for (int kb = 0; kb < 128; kb += 64) {
        __syncthreads();
        for (int i = t; i < 64 * 128; i += 256)
            Ws[i] = W[(kb + (i >> 7)) * HID + (i & 127)];
        __syncthreads();
        #pragma unroll 4
        for (int kk = 0; kk < 64; ++kk) {
            int k = kb + kk;
            float4 w = *(const float4*)&Ws[kk * 128 + f0];
            float4 r = *(const float4*)&rT[k * 36 + m0];
            acc[0][0] += r.x * w.x; acc[0][1] += r.x * w.y; acc[0][2] += r.x * w.z; acc[0][3] += r.x * w.w;
            acc[1][0] += r.y * w.x; acc[1][1] += r.y * w.y; acc[1][2] += r.y * w.z; acc[1][3] += r.y * w.w;
            acc[2][0] += r.z * w.x; acc[2][1] += r.z * w.y; acc[2][2] += r.z * w.z; acc[2][3] += r.z * w.w;
            acc[3][0] += r.w * w.x; acc[3][1] += r.w * w.y; acc[3][2] += r.w * w.z; acc[3][3] += r.w * w.w;
        }
    }

    float4 bb = *(const float4*)&bias[f0];
    #pragma unroll
    for (int j = 0; j < 4; ++j) {
        int node = base + m0 + j;
        if (node < N_NODES) {
            uint2 p;
            p.x = pack_bf2(fmaxf(acc[j][0] + bb.x, 0.f), fmaxf(acc[j][1] + bb.y, 0.f));
            p.y = pack_bf2(fmaxf(acc[j][2] + bb.z, 0.f), fmaxf(acc[j][3] + bb.w, 0.f));
            *(uint2*)&outg[node * 64 + (f0 >> 1)] = p;
        }
    }
}

// ---------------- fused head: Wc = W4 @ Wlin, bc = b4 @ Wlin + blin ----------------

__global__ void k_wc(const float* __restrict__ W4, const float* __restrict__ b4,
                     const float* __restrict__ Wlin, const float* __restrict__ blin,
                     float* __restrict__ Wc, float* __restrict__ bc) {
    int t = threadIdx.x;   // 256 threads: t = k*2 + o
    int k = t >> 1, o = t & 1;
    float acc = 0.f;
    for (int j = 0; j < HID; ++j) acc += W4[k * 2 * 64 + j] * Wlin[j * 2 + o];
    // note: W4 is [HID][HID] row-major = k*HID + j
    acc = 0.f;
    for (int j = 0; j < HID; ++j) acc += W4[k * HID + j] * Wlin[j * 2 + o];
    Wc[k * 2 + o] = acc;
    if (k == 0) {
        float b = blin[o];
        for (int j = 0; j < HID; ++j) b += b4[j] * Wlin[j * 2 + o];
        bc[o] = b;
    }
}

// ---------------- pool stage 1: per-chunk partial sums (atomic flush at boundaries) --

__global__ __launch_bounds__(256) void k_poolsum(const float* __restrict__ agg,
                                                 const int* __restrict__ batch,
                                                 float* __restrict__ pooled) {
    int wid = (blockIdx.x * blockDim.x + threadIdx.x) >> 6;   // wave id: 16 nodes each
    int lane = threadIdx.x & 63;
    int n0 = wid * 16;
    if (n0 >= N_NODES) return;
    int n1 = n0 + 16; if (n1 > N_NODES) n1 = N_NODES;
    int curg = batch[n0];
    float ax = 0.f, ay = 0.f;
    for (int n = n0; n < n1; ++n) {
        int g = batch[n];
        if (g != curg) {
            atomicAdd(&pooled[curg * HID + 2 * lane], ax);
            atomicAdd(&pooled[curg * HID + 2 * lane + 1], ay);
            ax = 0.f; ay = 0.f; curg = g;
        }
        float2 v = *(const float2*)&agg[(size_t)n * HID + 2 * lane];
        ax += v.x; ay += v.y;
    }
    atomicAdd(&pooled[curg * HID + 2 * lane], ax);
    atomicAdd(&pooled[curg * HID + 2 * lane + 1], ay);
}

// ---------------- pool stage 2: mean + fused W4*Wlin head ----------------

__global__ void k_head(const float* __restrict__ pooled, const int* __restrict__ batch,
                       const float* __restrict__ Wc, const float* __restrict__ bc,
                       const float* __restrict__ blin, float* __restrict__ out) {
    int wid = (blockIdx.x * blockDim.x + threadIdx.x) >> 6;
    int lane = threadIdx.x & 63;
    if (wid >= NG) return;
    int g = wid;
    int lo = 0, hi = N_NODES;
    while (lo < hi) { int mid = (lo + hi) >> 1; if (batch[mid] < g) lo = mid + 1; else hi = mid; }
    int start = lo;
    hi = N_NODES;
    while (lo < hi) { int mid = (lo + hi) >> 1; if (batch[mid] < g + 1) lo = mid + 1; else hi = mid; }
    int cnt = lo - start;
    float invc = (cnt > 0) ? 1.0f / (float)cnt : 0.f;
    float px = pooled[g * HID + 2 * lane] * invc;
    float py = pooled[g * HID + 2 * lane + 1] * invc;

    #pragma unroll
    for (int o = 0; o < 2; ++o) {
        float v = px * Wc[(2 * lane) * 2 + o] + py * Wc[(2 * lane + 1) * 2 + o];
        #pragma unroll
        for (int s = 32; s > 0; s >>= 1) v += __shfl_down(v, s);
        if (lane == 0) out[g * 2 + o] = (cnt > 0) ? (v + bc[o]) : blin[o];
    }
}

// ---------------- launcher ----------------

extern "C" void kernel_launch(void* const* d_in, const int* in_sizes, int n_in,
                              void* d_out, int out_size, void* d_ws, size_t ws_size,
                              hipStream_t stream) {
    const float* x    = (const float*)d_in[0];
    const int*   eidx = (const int*)d_in[1];
    const int*   batch= (const int*)d_in[2];
    const float* W1   = (const float*)d_in[3];
    const float* b1   = (const float*)d_in[4];
    const float* W2   = (const float*)d_in[5];
    const float* b2   = (const float*)d_in[6];
    const float* W3   = (const float*)d_in[7];
    const float* b3   = (const float*)d_in[8];
    const float* W4   = (const float*)d_in[9];
    const float* b4   = (const float*)d_in[10];
    const float* Wlin = (const float*)d_in[11];
    const float* blin = (const float*)d_in[12];
    float* out = (float*)d_out;

    // workspace carve-up (256B aligned)
    char* ws = (char*)d_ws;
    size_t off = 0;
    auto carve = [&](size_t bytes) { char* p = ws + off; off = (off + bytes + 255) & ~(size_t)255; return p; };
    int*   rowptr    = (int*)carve((size_t)(N_NODES + 1) * 4);
    float* dinv      = (float*)carve((size_t)N_NODES * 4);
    int*   col       = (int*)carve((size_t)E_EDGES * 4);
    unsigned int* ebuf = (unsigned int*)carve((size_t)E_EDGES * 4);
    int*   table     = (int*)carve((size_t)TLEN * 4);
    int*   partial   = (int*)carve((size_t)NCH * 4);
    int*   bucketBase= (int*)carve((size_t)(NBUCK + 1) * 4);
    float* aggx      = (float*)carve((size_t)N_NODES * FIN * 4);
    float* aggOut    = (float*)carve((size_t)N_NODES * HID * 4);
    char*  gpair     = carve((size_t)N_NODES * HID * 4);   // 2 bf16 g-buffers
    unsigned int* gA = (unsigned int*)gpair;
    unsigned int* gB = (unsigned int*)(gpair + (size_t)N_NODES * HID * 2);
    float* pooled    = (float*)carve((size_t)NG * HID * 4);
    float* Wc        = (float*)carve((size_t)HID * 2 * 4);
    float* bc        = (float*)carve(2 * 4);
    (void)ws_size; (void)n_in; (void)in_sizes; (void)out_size;

    const int BLK = 256;
    int gridN = (N_NODES + BLK - 1) / BLK;
    int gridAgg = (N_NODES * 64 + BLK - 1) / BLK;
    int gridMM = (N_NODES + 31) / 32;
    int gridMM1 = (N_NODES * 64 + BLK - 1) / BLK;
    int gridPS = ((N_NODES + 15) / 16 * 64 + BLK - 1) / BLK;
    int gridHead = (NG * 64 + BLK - 1) / BLK;

    // CSR build (radix partition: hist -> scan -> scatter -> bucket finalize)
    k_hist2<<<NBLK_SC, BLK, 0, stream>>>(eidx, table);
    k_blocksum<<<NCH, BLK, 0, stream>>>(table, partial);
    k_scan_blk<<<1, 64, 0, stream>>>(partial);
    k_scan_final<<<NCH, 1024, 0, stream>>>(table, partial);
    k_bbase<<<1, 1024, 0, stream>>>(table, bucketBase, rowptr);
    k_scatter2<<<NBLK_SC, BLK, 0, stream>>>(eidx, table, ebuf);
    k_bucket<<<NBUCK, BLK, 0, stream>>>(ebuf, bucketBase, rowptr, dinv, col);

    // head weight folding (independent of graph pipeline)
    k_wc<<<1, 256, 0, stream>>>(W4, b4, Wlin, blin, Wc, bc);
    hipMemsetAsync(pooled, 0, (size_t)NG * HID * 4, stream);

    // layer 1: g1 = bf16(relu((A' x) W1 + b1))
    k_agg7<<<gridN, BLK, 0, stream>>>(x, rowptr, col, dinv, aggx);
    k_mm1<<<gridMM1, BLK, 0, stream>>>(aggx, W1, b1, gA);

    // layer 2: g2 = bf16(relu((A' g1) W2 + b2))
    k_agg128<<<gridAgg, BLK, 0, stream>>>(gA, aggOut, rowptr, col, dinv);
    k_mm128<<<gridMM, BLK, 0, stream>>>(aggOut, gB, W2, b2);
    // layer 3
    k_agg128<<<gridAgg, BLK, 0, stream>>>(gB, aggOut, rowptr, col, dinv);
    k_mm128<<<gridMM, BLK, 0, stream>>>(aggOut, gA, W3, b3);
    // layer 4 aggregation only (W4 folded into head)
    k_agg128<<<gridAgg, BLK, 0, stream>>>(gA, aggOut, rowptr, col, dinv);

    // pool + fused head
    k_poolsum<<<gridPS, BLK, 0, stream>>>(aggOut, batch, pooled);
    k_head<<<gridHead, BLK, 0, stream>>>(pooled, batch, Wc, bc, blin, out);
}

// Round 6
// 483.683 us; speedup vs baseline: 2.3156x; 1.1758x over previous
//
#include <hip/hip_runtime.h>
#include <hip/hip_bf16.h>

#define N_NODES 100000
#define E_EDGES 1600000
#define NG 512
#define FIN 7
#define HID 128
#define NBUCK 782          // ceil(N_NODES/128), bucket = 128 consecutive dst nodes
#define NBLK_SC 128        // partition blocks (each owns a contiguous edge chunk)
#define CHUNK 12500        // E_EDGES / NBLK_SC (exact)
#define TLEN (NBUCK * NBLK_SC)   // 100096 table entries
#define NCH 98             // ceil(TLEN/1024) scan chunks
#define MMX_GRID 782       // ceil(N_NODES/128)

typedef __attribute__((ext_vector_type(8))) short bf16x8;
typedef __attribute__((ext_vector_type(4))) float f32x4;

// bf16 helpers: decode packed pair, encode with RNE
__device__ __forceinline__ float bf_lo(unsigned int u) { return __uint_as_float(u << 16); }
__device__ __forceinline__ float bf_hi(unsigned int u) { return __uint_as_float(u & 0xffff0000u); }
__device__ __forceinline__ unsigned int f2bf_rne(float f) {
    unsigned int x = __float_as_uint(f);
    return (x + 0x7fffu + ((x >> 16) & 1u)) >> 16;   // finite inputs only
}
__device__ __forceinline__ unsigned int pack_bf2(float lo, float hi) {
    return f2bf_rne(lo) | (f2bf_rne(hi) << 16);
}

// ---------------- CSR build (radix partition) ----------------

__global__ __launch_bounds__(256) void k_hist2(const int* __restrict__ eidx,
                                               int* __restrict__ table) {
    __shared__ int h[NBUCK];
    int blk = blockIdx.x, t = threadIdx.x;
    for (int i = t; i < NBUCK; i += 256) h[i] = 0;
    __syncthreads();
    int e0 = blk * CHUNK, e1 = e0 + CHUNK;
    for (int e = e0 + t; e < e1; e += 256)
        atomicAdd(&h[eidx[E_EDGES + e] >> 7], 1);
    __syncthreads();
    for (int i = t; i < NBUCK; i += 256)
        table[i * NBLK_SC + blk] = h[i];
}

__global__ void k_blocksum(const int* __restrict__ table, int* __restrict__ partial) {
    __shared__ int s[256];
    int b = blockIdx.x, t = threadIdx.x;
    int base = b * 1024;
    int sum = 0;
    for (int i = t; i < 1024; i += 256) {
        int idx = base + i;
        sum += (idx < TLEN) ? table[idx] : 0;
    }
    s[t] = sum; __syncthreads();
    for (int st = 128; st > 0; st >>= 1) {
        if (t < st) s[t] += s[t + st];
        __syncthreads();
    }
    if (t == 0) partial[b] = s[0];
}

__global__ void k_scan_blk(int* __restrict__ partial) {
    if (threadIdx.x == 0 && blockIdx.x == 0) {
        int run = 0;
        for (int i = 0; i < NCH; ++i) { int v = partial[i]; partial[i] = run; run += v; }
    }
}

__global__ void k_scan_final(int* __restrict__ table, const int* __restrict__ partial) {
    __shared__ int s[1024];
    int b = blockIdx.x, t = threadIdx.x;
    int idx = b * 1024 + t;
    int v = (idx < TLEN) ? table[idx] : 0;
    s[t] = v; __syncthreads();
    for (int st = 1; st < 1024; st <<= 1) {
        int add = (t >= st) ? s[t - st] : 0;
        __syncthreads();
        s[t] += add;
        __syncthreads();
    }
    if (idx < TLEN) table[idx] = partial[b] + s[t] - v;   // exclusive
}

__global__ void k_bbase(const int* __restrict__ table, int* __restrict__ bucketBase,
                        int* __restrict__ rowptr) {
    int t = blockIdx.x * blockDim.x + threadIdx.x;
    if (t < NBUCK) bucketBase[t] = table[t * NBLK_SC];
    if (t == 0) { bucketBase[NBUCK] = E_EDGES; rowptr[N_NODES] = E_EDGES; }
}

__global__ __launch_bounds__(256) void k_scatter2(const int* __restrict__ eidx,
                                                  const int* __restrict__ table,
                                                  unsigned int* __restrict__ ebuf) {
    __shared__ int loff[NBUCK];
    int blk = blockIdx.x, t = threadIdx.x;
    for (int i = t; i < NBUCK; i += 256) loff[i] = table[i * NBLK_SC + blk];
    __syncthreads();
    int e0 = blk * CHUNK, e1 = e0 + CHUNK;
    for (int e = e0 + t; e < e1; e += 256) {
        int s = eidx[e];
        int d = eidx[E_EDGES + e];
        int p = atomicAdd(&loff[d >> 7], 1);
        ebuf[p] = ((unsigned int)(d & 127) << 17) | (unsigned int)s;
    }
}

__global__ __launch_bounds__(256) void k_bucket(const unsigned int* __restrict__ ebuf,
                                                const int* __restrict__ bucketBase,
                                                int* __restrict__ rowptr,
                                                float* __restrict__ dinv,
                                                int* __restrict__ col) {
    __shared__ int scnt[128], soff[128], scur[128];
    int b = blockIdx.x, t = threadIdx.x;
    int bbase = bucketBase[b], bend = bucketBase[b + 1];
    if (t < 128) { scnt[t] = 0; scur[t] = 0; }
    __syncthreads();
    for (int e = bbase + t; e < bend; e += 256) {
        unsigned int rec = ebuf[e];
        atomicAdd(&scnt[rec >> 17], 1);
    }
    __syncthreads();
    if (t < 128) soff[t] = scnt[t];
    __syncthreads();
    for (int st = 1; st < 128; st <<= 1) {
        int a = (t < 128 && t >= st) ? soff[t - st] : 0;
        __syncthreads();
        if (t < 128) soff[t] += a;
        __syncthreads();
    }
    if (t < 128) {
        int ex = soff[t] - scnt[t];
        int node = b * 128 + t;
        if (node < N_NODES) {
            rowptr[node] = bbase + ex;
            dinv[node] = rsqrtf((float)(scnt[t] + 1));   // +1 self-loop
        }
        soff[t] = ex;
    }
    __syncthreads();
    for (int e = bbase + t; e < bend; e += 256) {
        unsigned int rec = ebuf[e];
        int dl = rec >> 17;
        int s = rec & 0x1FFFF;
        int p = bbase + soff[dl] + atomicAdd(&scur[dl], 1);
        col[p] = s;
    }
}

// ---------------- layer 1 aggregation (7-wide, fp32 x) ----------------

__global__ void k_agg7(const float* __restrict__ x, const int* __restrict__ rowptr,
                       const int* __restrict__ col, const float* __restrict__ dinv,
                       float* __restrict__ aggx) {
    int i = blockIdx.x * blockDim.x + threadIdx.x;
    if (i >= N_NODES) return;
    float di = dinv[i];
    float a[FIN];
    #pragma unroll
    for (int f = 0; f < FIN; ++f) a[f] = di * x[i * FIN + f];
    int e0 = rowptr[i], e1 = rowptr[i + 1];
    for (int e = e0; e < e1; ++e) {
        int s = col[e];
        float ds = dinv[s];
        #pragma unroll
        for (int f = 0; f < FIN; ++f) a[f] += ds * x[s * FIN + f];
    }
    #pragma unroll
    for (int f = 0; f < FIN; ++f) aggx[i * FIN + f] = di * a[f];
}

// layer-1 matmul: out = relu(aggx @ W1 + b1) cast to packed bf16
__global__ void k_mm1(const float* __restrict__ aggx, const float* __restrict__ W1,
                      const float* __restrict__ b1, unsigned int* __restrict__ g1) {
    int idx = blockIdx.x * blockDim.x + threadIdx.x;   // N*64 threads
    if (idx >= N_NODES * 64) return;
    int n = idx >> 6, fp = idx & 63;
    int f0 = 2 * fp;
    float acc0 = b1[f0], acc1 = b1[f0 + 1];
    #pragma unroll
    for (int k = 0; k < FIN; ++k) {
        float a = aggx[n * FIN + k];
        acc0 += a * W1[k * HID + f0];
        acc1 += a * W1[k * HID + f0 + 1];
    }
    g1[idx] = pack_bf2(fmaxf(acc0, 0.f), fmaxf(acc1, 0.f));
}

// ---------------- 128-wide aggregation (wave/node, bf16 gather, shfl-batched) --------
// BF16OUT=true : writes hi/lo bf16 planes (split-precision MFMA A operand)
// BF16OUT=false: writes fp32 (layer 4, feeds pooling)

template <bool BF16OUT>
__global__ void k_agg128(const unsigned int* __restrict__ g,   // packed bf16 pairs [N][64]
                         unsigned int* __restrict__ oH, unsigned int* __restrict__ oL,
                         float* __restrict__ oF,
                         const int* __restrict__ rowptr, const int* __restrict__ col,
                         const float* __restrict__ dinv) {
    int wid = (blockIdx.x * blockDim.x + threadIdx.x) >> 6;
    int lane = threadIdx.x & 63;
    if (wid >= N_NODES) return;
    int i = wid;
    float di = dinv[i];
    unsigned int v = g[(size_t)i * 64 + lane];
    float ax = di * bf_lo(v), ay = di * bf_hi(v);
    int e0 = rowptr[i], e1 = rowptr[i + 1];
    for (int base = e0; base < e1; base += 64) {
        int m = e1 - base; if (m > 64) m = 64;
        int sc = 0; float dsv = 0.f;
        if (lane < m) { sc = col[base + lane]; dsv = dinv[sc]; }
        int j = 0;
        for (; j + 3 < m; j += 4) {
            int s0 = __shfl(sc, j),     s1 = __shfl(sc, j + 1);
            int s2 = __shfl(sc, j + 2), s3 = __shfl(sc, j + 3);
            float d0 = __shfl(dsv, j),     d1 = __shfl(dsv, j + 1);
            float d2 = __shfl(dsv, j + 2), d3 = __shfl(dsv, j + 3);
            unsigned int u0 = g[(size_t)s0 * 64 + lane];
            unsigned int u1 = g[(size_t)s1 * 64 + lane];
            unsigned int u2 = g[(size_t)s2 * 64 + lane];
            unsigned int u3 = g[(size_t)s3 * 64 + lane];
            ax += d0 * bf_lo(u0); ay += d0 * bf_hi(u0);
            ax += d1 * bf_lo(u1); ay += d1 * bf_hi(u1);
            ax += d2 * bf_lo(u2); ay += d2 * bf_hi(u2);
            ax += d3 * bf_lo(u3); ay += d3 * bf_hi(u3);
        }
        for (; j < m; ++j) {
            int s0 = __shfl(sc, j);
            float d0 = __shfl(dsv, j);
            unsigned int u0 = g[(size_t)s0 * 64 + lane];
            ax += d0 * bf_lo(u0); ay += d0 * bf_hi(u0);
        }
    }
    float ox = di * ax, oy = di * ay;
    if (BF16OUT) {
        unsigned int hx = f2bf_rne(ox), hy = f2bf_rne(oy);
        float rx = ox - __uint_as_float(hx << 16);
        float ry = oy - __uint_as_float(hy << 16);
        oH[(size_t)i * 64 + lane] = hx | (hy << 16);
        oL[(size_t)i * 64 + lane] = pack_bf2(rx, ry);
    } else {
        float2 o; o.x = ox; o.y = oy;
        *(float2*)&oF[(size_t)i * HID + 2 * lane] = o;
    }
}

// ---------------- MFMA matmul (layers 2,3): g_out = bf16(relu((Ahi+Alo) @ W + b)) -----
// Wave: 32 nodes x 128 feats; block: 4 waves = 128 nodes. W staged transposed in LDS.

__global__ __launch_bounds__(256) void k_mmx(const unsigned int* __restrict__ gH,
                                             const unsigned int* __restrict__ gL,
                                             const float* __restrict__ W,
                                             const float* __restrict__ bias,
                                             unsigned int* __restrict__ outg) {
    __shared__ unsigned short sbuf[128 * 136];   // 34816 B: WT (stride 136), reused as Cs (stride 132)
    int t = threadIdx.x;
    // stage W transposed as bf16: WT[n*136 + k] = bf16(W[k][n])
    for (int i = t; i < 128 * 128; i += 256) {
        int k = i >> 7, n = i & 127;
        sbuf[n * 136 + k] = (unsigned short)f2bf_rne(W[i]);
    }

    int lane = t & 63, wave = t >> 6;
    int m = lane & 15, quad = lane >> 4;
    int nodeBase = blockIdx.x * 128 + wave * 32;
    const short* gHs = (const short*)gH;
    const short* gLs = (const short*)gL;

    float bi[8];
    #pragma unroll
    for (int nt = 0; nt < 8; ++nt) bi[nt] = bias[nt * 16 + m];

    f32x4 acc[2][8];
    #pragma unroll
    for (int gi = 0; gi < 2; ++gi)
        #pragma unroll
        for (int nt = 0; nt < 8; ++nt)
            acc[gi][nt] = (f32x4){0.f, 0.f, 0.f, 0.f};

    __syncthreads();

    #pragma unroll
    for (int kc = 0; kc < 4; ++kc) {
        bf16x8 ah[2], al[2];
        #pragma unroll
        for (int gi = 0; gi < 2; ++gi) {
            int node = nodeBase + gi * 16 + m;
            bf16x8 h = {0, 0, 0, 0, 0, 0, 0, 0};
            bf16x8 l = {0, 0, 0, 0, 0, 0, 0, 0};
            if (node < N_NODES) {
                size_t boff = (size_t)node * 128 + kc * 32 + quad * 8;
                h = *(const bf16x8*)(gHs + boff);
                l = *(const bf16x8*)(gLs + boff);
            }
            ah[gi] = h; al[gi] = l;
        }
        #pragma unroll
        for (int nt = 0; nt < 8; ++nt) {
            bf16x8 b = *(const bf16x8*)(sbuf + (nt * 16 + m) * 136 + kc * 32 + quad * 8);
            #pragma unroll
            for (int gi = 0; gi < 2; ++gi) {
                acc[gi][nt] = __builtin_amdgcn_mfma_f32_16x16x32_bf16(al[gi], b, acc[gi][nt], 0, 0, 0);
                acc[gi][nt] = __builtin_amdgcn_mfma_f32_16x16x32_bf16(ah[gi], b, acc[gi][nt], 0, 0, 0);
            }
        }
    }

    __syncthreads();   // all waves done reading WT
    // epilogue: bias+relu+bf16, scatter to Cs[node_local][feat], stride 132
    // C/D layout: col=lane&15 (feat m), row=quad*4+reg (node within 16-group)
    #pragma unroll
    for (int gi = 0; gi < 2; ++gi)
        #pragma unroll
        for (int nt = 0; nt < 8; ++nt)
            #pragma unroll
            for (int r = 0; r < 4; ++r) {
                int nl = wave * 32 + gi * 16 + quad * 4 + r;
                float vv = acc[gi][nt][r] + bi[nt];
                sbuf[nl * 132 + nt * 16 + m] = (unsigned short)f2bf_rne(fmaxf(vv, 0.f));
            }
    __syncthreads();
    // cooperative coalesced store: 4 bf16 (uint2) per iteration
    for (int i = t; i < 128 * 32; i += 256) {
        int nl = i >> 5, p = i & 31;
        int node = blockIdx.x * 128 + nl;
        if (node < N_NODES) {
            uint2 val = *(const uint2*)(sbuf + nl * 132 + p * 4);
            *(uint2*)&outg[(size_t)node * 64 + p * 2] = val;
        }
    }
}

// ---------------- fused head: Wc = W4 @ Wlin, bc = b4 @ Wlin + blin ----------------

__global__ void k_wc(const float* __restrict__ W4, const float* __restrict__ b4,
                     const float* __restrict__ Wlin, const float* __restrict__ blin,
                     float* __restrict__ Wc, float* __restrict__ bc) {
    int t = threadIdx.x;   // 256 threads: t = k*2 + o
    int k = t >> 1, o = t & 1;
    float acc = 0.f;
    for (int j = 0; j < HID; ++j) acc += W4[k * HID + j] * Wlin[j * 2 + o];
    Wc[k * 2 + o] = acc;
    if (k == 0) {
        float b = blin[o];
        for (int j = 0; j < HID; ++j) b += b4[j] * Wlin[j * 2 + o];
        bc[o] = b;
    }
}

// ---------------- pool stage 1: per-chunk partial sums (atomic flush at boundaries) --

__global__ __launch_bounds__(256) void k_poolsum(const float* __restrict__ agg,
                                                 const int* __restrict__ batch,
                                                 float* __restrict__ pooled) {
    int wid = (blockIdx.x * blockDim.x + threadIdx.x) >> 6;   // wave id: 16 nodes each
    int lane = threadIdx.x & 63;
    int n0 = wid * 16;
    if (n0 >= N_NODES) return;
    int n1 = n0 + 16; if (n1 > N_NODES) n1 = N_NODES;
    int curg = batch[n0];
    float ax = 0.f, ay = 0.f;
    for (int n = n0; n < n1; ++n) {
        int g = batch[n];
        if (g != curg) {
            atomicAdd(&pooled[curg * HID + 2 * lane], ax);
            atomicAdd(&pooled[curg * HID + 2 * lane + 1], ay);
            ax = 0.f; ay = 0.f; curg = g;
        }
        float2 v = *(const float2*)&agg[(size_t)n * HID + 2 * lane];
        ax += v.x; ay += v.y;
    }
    atomicAdd(&pooled[curg * HID + 2 * lane], ax);
    atomicAdd(&pooled[curg * HID + 2 * lane + 1], ay);
}

// ---------------- pool stage 2: mean + fused W4*Wlin head ----------------

__global__ void k_head(const float* __restrict__ pooled, const int* __restrict__ batch,
                       const float* __restrict__ Wc, const float* __restrict__ bc,
                       const float* __restrict__ blin, float* __restrict__ out) {
    int wid = (blockIdx.x * blockDim.x + threadIdx.x) >> 6;
    int lane = threadIdx.x & 63;
    if (wid >= NG) return;
    int g = wid;
    int lo = 0, hi = N_NODES;
    while (lo < hi) { int mid = (lo + hi) >> 1; if (batch[mid] < g) lo = mid + 1; else hi = mid; }
    int start = lo;
    hi = N_NODES;
    while (lo < hi) { int mid = (lo + hi) >> 1; if (batch[mid] < g + 1) lo = mid + 1; else hi = mid; }
    int cnt = lo - start;
    float invc = (cnt > 0) ? 1.0f / (float)cnt : 0.f;
    float px = pooled[g * HID + 2 * lane] * invc;
    float py = pooled[g * HID + 2 * lane + 1] * invc;

    #pragma unroll
    for (int o = 0; o < 2; ++o) {
        float v = px * Wc[(2 * lane) * 2 + o] + py * Wc[(2 * lane + 1) * 2 + o];
        #pragma unroll
        for (int s = 32; s > 0; s >>= 1) v += __shfl_down(v, s);
        if (lane == 0) out[g * 2 + o] = (cnt > 0) ? (v + bc[o]) : blin[o];
    }
}

// ---------------- launcher ----------------

extern "C" void kernel_launch(void* const* d_in, const int* in_sizes, int n_in,
                              void* d_out, int out_size, void* d_ws, size_t ws_size,
                              hipStream_t stream) {
    const float* x    = (const float*)d_in[0];
    const int*   eidx = (const int*)d_in[1];
    const int*   batch= (const int*)d_in[2];
    const float* W1   = (const float*)d_in[3];
    const float* b1   = (const float*)d_in[4];
    const float* W2   = (const float*)d_in[5];
    const float* b2   = (const float*)d_in[6];
    const float* W3   = (const float*)d_in[7];
    const float* b3   = (const float*)d_in[8];
    const float* W4   = (const float*)d_in[9];
    const float* b4   = (const float*)d_in[10];
    const float* Wlin = (const float*)d_in[11];
    const float* blin = (const float*)d_in[12];
    float* out = (float*)d_out;

    // workspace carve-up (256B aligned)
    char* ws = (char*)d_ws;
    size_t off = 0;
    auto carve = [&](size_t bytes) { char* p = ws + off; off = (off + bytes + 255) & ~(size_t)255; return p; };
    int*   rowptr    = (int*)carve((size_t)(N_NODES + 1) * 4);
    float* dinv      = (float*)carve((size_t)N_NODES * 4);
    int*   col       = (int*)carve((size_t)E_EDGES * 4);
    unsigned int* ebuf = (unsigned int*)carve((size_t)E_EDGES * 4);
    int*   table     = (int*)carve((size_t)TLEN * 4);
    int*   partial   = (int*)carve((size_t)NCH * 4);
    int*   bucketBase= (int*)carve((size_t)(NBUCK + 1) * 4);
    float* aggx      = (float*)carve((size_t)N_NODES * FIN * 4);
    unsigned int* gA = (unsigned int*)carve((size_t)N_NODES * 64 * 4);   // 25.6 MB bf16 g-buffer
    unsigned int* gB = (unsigned int*)carve((size_t)N_NODES * 64 * 4);   // 25.6 MB
    char*  hlpair    = carve((size_t)N_NODES * 64 * 8);                  // gH+gL (51.2 MB), aliased by aggOut
    unsigned int* gH = (unsigned int*)hlpair;
    unsigned int* gL = (unsigned int*)(hlpair + (size_t)N_NODES * 64 * 4);
    float* aggOut    = (float*)hlpair;   // layer-4 fp32 agg; gH/gL dead by then
    float* pooled    = (float*)carve((size_t)NG * HID * 4);
    float* Wc        = (float*)carve((size_t)HID * 2 * 4);
    float* bc        = (float*)carve(2 * 4);
    (void)ws_size; (void)n_in; (void)in_sizes; (void)out_size;

    const int BLK = 256;
    int gridN = (N_NODES + BLK - 1) / BLK;
    int gridAgg = (N_NODES * 64 + BLK - 1) / BLK;
    int gridMM1 = (N_NODES * 64 + BLK - 1) / BLK;
    int gridPS = ((N_NODES + 15) / 16 * 64 + BLK - 1) / BLK;
    int gridHead = (NG * 64 + BLK - 1) / BLK;

    // CSR build (radix partition: hist -> scan -> scatter -> bucket finalize)
    k_hist2<<<NBLK_SC, BLK, 0, stream>>>(eidx, table);
    k_blocksum<<<NCH, BLK, 0, stream>>>(table, partial);
    k_scan_blk<<<1, 64, 0, stream>>>(partial);
    k_scan_final<<<NCH, 1024, 0, stream>>>(table, partial);
    k_bbase<<<1, 1024, 0, stream>>>(table, bucketBase, rowptr);
    k_scatter2<<<NBLK_SC, BLK, 0, stream>>>(eidx, table, ebuf);
    k_bucket<<<NBUCK, BLK, 0, stream>>>(ebuf, bucketBase, rowptr, dinv, col);

    // head weight folding (independent of graph pipeline)
    k_wc<<<1, 256, 0, stream>>>(W4, b4, Wlin, blin, Wc, bc);
    hipMemsetAsync(pooled, 0, (size_t)NG * HID * 4, stream);

    // layer 1: g1 = bf16(relu((A' x) W1 + b1))
    k_agg7<<<gridN, BLK, 0, stream>>>(x, rowptr, col, dinv, aggx);
    k_mm1<<<gridMM1, BLK, 0, stream>>>(aggx, W1, b1, gA);

    // layer 2: agg (hi/lo) -> MFMA mm -> g2
    k_agg128<true><<<gridAgg, BLK, 0, stream>>>(gA, gH, gL, nullptr, rowptr, col, dinv);
    k_mmx<<<MMX_GRID, BLK, 0, stream>>>(gH, gL, W2, b2, gB);
    // layer 3
    k_agg128<true><<<gridAgg, BLK, 0, stream>>>(gB, gH, gL, nullptr, rowptr, col, dinv);
    k_mmx<<<MMX_GRID, BLK, 0, stream>>>(gH, gL, W3, b3, gA);
    // layer 4: aggregation only (W4 folded into head), fp32 out
    k_agg128<false><<<gridAgg, BLK, 0, stream>>>(gA, nullptr, nullptr, aggOut, rowptr, col, dinv);

    // pool + fused head
    k_poolsum<<<gridPS, BLK, 0, stream>>>(aggOut, batch, pooled);
    k_head<<<gridHead, BLK, 0, stream>>>(pooled, batch, Wc, bc, blin, out);
}